// Round 1
// baseline (316.081 us; speedup 1.0000x reference)
//
#include <hip/hip_runtime.h>
#include <hip/hip_bf16.h>
#include <cstdint>

typedef __bf16 bf16;
typedef __bf16 bf16x8 __attribute__((ext_vector_type(8)));
typedef float f32x4 __attribute__((ext_vector_type(4)));

#define B_ 16
#define N_ 1024
#define FEAT_ 768
#define H_ 8
#define NONGT_ 20
#define M_ 10
#define POS_ 64
#define DG_ 96
#define KTOT_ 30
#define KPAD_ 32
#define ROWS_ (B_*N_)
#define SCALE_M 9.797958971132712f
#define INV_SQRT_DG 0.10206207261596575f
#define NEG_ -9.0e15f

__device__ __forceinline__ void gload16(const void* g, void* lds) {
  __builtin_amdgcn_global_load_lds(
      (const __attribute__((address_space(1))) unsigned int*)g,
      (__attribute__((address_space(3))) unsigned int*)lds, 16, 0, 0);
}

__device__ __forceinline__ unsigned short bfbits(bf16 x) {
  union { bf16 b; unsigned short u; } c; c.b = x; return c.u;
}
__device__ __forceinline__ float bflo(unsigned int u) { return __uint_as_float(u << 16); }
__device__ __forceinline__ float bfhi(unsigned int u) { return __uint_as_float(u & 0xffff0000u); }
__device__ __forceinline__ float dot8(uint4 a, uint4 b) {
  float s = bflo(a.x)*bflo(b.x) + bfhi(a.x)*bfhi(b.x);
  s += bflo(a.y)*bflo(b.y) + bfhi(a.y)*bfhi(b.y);
  s += bflo(a.z)*bflo(b.z) + bfhi(a.z)*bfhi(b.z);
  s += bflo(a.w)*bflo(b.w) + bfhi(a.w)*bfhi(b.w);
  return s;
}

// ---------------- prep: weight transposes/conversions + V build ----------------
__global__ void prep_kernel(const float* __restrict__ Wq, const float* __restrict__ Wk,
                            const float* __restrict__ Wout, const float* __restrict__ roi,
                            const float* __restrict__ aux, const float* __restrict__ m_v,
                            bf16* __restrict__ Wq_t, bf16* __restrict__ Wk_t,
                            bf16* __restrict__ Whi, bf16* __restrict__ Wlo,
                            bf16* __restrict__ Vbf)
{
  int idx = blockIdx.x * blockDim.x + threadIdx.x;
  int stride = gridDim.x * blockDim.x;
  for (int i = idx; i < FEAT_*FEAT_; i += stride) {
    int n = i / FEAT_, k = i % FEAT_;
    Wq_t[i] = (bf16)Wq[k*FEAT_ + n];
    Wk_t[i] = (bf16)Wk[k*FEAT_ + n];
    float w = Wout[i];              // Wout is [(h*DG+g)][f] row-major already
    bf16 hi = (bf16)w;
    Whi[i] = hi;
    Wlo[i] = (bf16)(w - (float)hi);
  }
  for (int i = idx; i < B_*KPAD_*FEAT_; i += stride) {
    int f = i % FEAT_;
    int r = (i / FEAT_) % KPAD_;
    int b = i / (FEAT_*KPAD_);
    float v;
    if (r < NONGT_)      v = roi[((size_t)b*N_ + r)*FEAT_ + f];
    else if (r < KTOT_)  v = SCALE_M * m_v[(r-NONGT_)*FEAT_ + f] * aux[b*FEAT_ + f];
    else                 v = 0.f;
    Vbf[i] = (bf16)v;
  }
}

// ---------------- roi -> bf16 ----------------
__global__ void convert_roi_kernel(const float* __restrict__ roi, bf16* __restrict__ Abf) {
  int idx = blockIdx.x * blockDim.x + threadIdx.x;
  const int total8 = ROWS_*FEAT_/8;
  int stride = gridDim.x * blockDim.x;
  for (int i = idx; i < total8; i += stride) {
    const float4* p = (const float4*)(roi + (size_t)i*8);
    float4 x = p[0], y = p[1];
    bf16x8 o;
    o[0]=(bf16)x.x; o[1]=(bf16)x.y; o[2]=(bf16)x.z; o[3]=(bf16)x.w;
    o[4]=(bf16)y.x; o[5]=(bf16)y.y; o[6]=(bf16)y.z; o[7]=(bf16)y.w;
    *(bf16x8*)(Abf + (size_t)i*8) = o;
  }
}

// ---------------- 128x128 bf16 MFMA GEMM: C = A @ Bm^T + bias (bf16 out) ----------------
__global__ __launch_bounds__(256, 2) void gemm128_kernel(
    const bf16* __restrict__ A, const bf16* __restrict__ Bm,
    const float* __restrict__ bias, bf16* __restrict__ C)
{
  __shared__ __align__(16) bf16 sA[128*32];
  __shared__ __align__(16) bf16 sB[128*32];
  const int tid = threadIdx.x;
  const int w = tid >> 6, l = tid & 63;
  const int mbase = blockIdx.y * 128;
  const int nbase = blockIdx.x * 128;
  const int wr = w >> 1, wc = w & 1;
  const int srow = tid >> 2;
  const int scol = (tid & 3) << 3;
  const bf16* Ag0 = A + (size_t)(mbase + srow)*FEAT_ + scol;
  const bf16* Ag1 = Ag0 + (size_t)64*FEAT_;
  const bf16* Bg0 = Bm + (size_t)(nbase + srow)*FEAT_ + scol;
  const bf16* Bg1 = Bg0 + (size_t)64*FEAT_;
  bf16* ldsA0 = sA + w*512;
  bf16* ldsA1 = sA + 2048 + w*512;
  bf16* ldsB0 = sB + w*512;
  bf16* ldsB1 = sB + 2048 + w*512;
  const int fr = l & 15, fko = (l >> 4) << 3;
  f32x4 acc[4][4] = {};
  for (int kt = 0; kt < FEAT_/32; ++kt) {
    __syncthreads();
    gload16(Ag0 + kt*32, ldsA0);
    gload16(Ag1 + kt*32, ldsA1);
    gload16(Bg0 + kt*32, ldsB0);
    gload16(Bg1 + kt*32, ldsB1);
    __syncthreads();
    bf16x8 af[4], bff[4];
    #pragma unroll
    for (int m = 0; m < 4; ++m)
      af[m] = *(const bf16x8*)(sA + (wr*64 + m*16 + fr)*32 + fko);
    #pragma unroll
    for (int n = 0; n < 4; ++n)
      bff[n] = *(const bf16x8*)(sB + (wc*64 + n*16 + fr)*32 + fko);
    #pragma unroll
    for (int m = 0; m < 4; ++m) {
      #pragma unroll
      for (int n = 0; n < 4; ++n)
        acc[m][n] = __builtin_amdgcn_mfma_f32_16x16x32_bf16(af[m], bff[n], acc[m][n], 0, 0, 0);
    }
  }
  const int fq = l >> 4;
  #pragma unroll
  for (int n = 0; n < 4; ++n) {
    const int col = nbase + wc*64 + n*16 + fr;
    const float bv = bias[col];
    #pragma unroll
    for (int m = 0; m < 4; ++m) {
      const int row = mbase + wr*64 + m*16 + fq*4;
      #pragma unroll
      for (int r = 0; r < 4; ++r)
        C[(size_t)(row + r)*FEAT_ + col] = (bf16)(acc[m][n][r] + bv);
    }
  }
}

// ---------------- small GEMM (1 wave, 16x128 tile): C(f32) = A @ B1^T [+ A @ B2^T] + bias ----
__global__ __launch_bounds__(64, 4) void gemm_small_kernel(
    const bf16* __restrict__ A, const bf16* __restrict__ B1, const bf16* __restrict__ B2,
    const float* __restrict__ bias, float* __restrict__ C, int mode)
{
  const int l = threadIdx.x;
  const int bm = blockIdx.y;
  const int nbase = blockIdx.x * 128;
  const int arow_base = (mode == 1) ? ((bm >> 1)*N_ + (bm & 1)*16) : (bm*16);
  const int orow_base = bm * 16;
  const int fr = l & 15, fko = (l >> 4) << 3;
  const bf16* Ap = A + (size_t)(arow_base + fr)*FEAT_ + fko;
  f32x4 acc[8] = {};
  const int npass = B2 ? 2 : 1;
  for (int pass = 0; pass < npass; ++pass) {
    const bf16* Bp = (pass ? B2 : B1) + (size_t)(nbase + fr)*FEAT_ + fko;
    for (int kt = 0; kt < FEAT_/32; ++kt) {
      bf16x8 a = *(const bf16x8*)(Ap + kt*32);
      #pragma unroll
      for (int n = 0; n < 8; ++n) {
        bf16x8 b = *(const bf16x8*)(Bp + kt*32 + (size_t)n*16*FEAT_);
        acc[n] = __builtin_amdgcn_mfma_f32_16x16x32_bf16(a, b, acc[n], 0, 0, 0);
      }
    }
  }
  const int fq = l >> 4;
  #pragma unroll
  for (int n = 0; n < 8; ++n) {
    const int col = nbase + n*16 + fr;
    const float bv = bias ? bias[col] : 0.f;
    #pragma unroll
    for (int r = 0; r < 4; ++r)
      C[(size_t)(orow_base + fq*4 + r)*FEAT_ + col] = acc[n][r] + bv;
  }
}

// ---------------- mk rows of kbuf ----------------
__global__ void fill_mk_kernel(const float* __restrict__ m_k, const float* __restrict__ aux,
                               float* __restrict__ kbuf)
{
  int idx = blockIdx.x * blockDim.x + threadIdx.x;
  const int total = B_*M_*FEAT_;
  if (idx >= total) return;
  int f = idx % FEAT_;
  int i = (idx / FEAT_) % M_;
  int b = idx / (FEAT_*M_);
  kbuf[((size_t)b*KPAD_ + NONGT_ + i)*FEAT_ + f] = SCALE_M * m_k[i*FEAT_ + f] * aux[b*FEAT_ + f];
}

// ---------------- position bias: log(max(relu(pe@Wpos+bpos),1e-6)) ----------------
__global__ __launch_bounds__(64, 4) void posbias_kernel(
    const float* __restrict__ pe, const float* __restrict__ Wpos,
    const float* __restrict__ bpos, float* __restrict__ posb)
{
  __shared__ __align__(16) float spe[NONGT_*68];
  __shared__ __align__(16) float swpT[H_*68];
  __shared__ float sbp[H_];
  const int row = blockIdx.x;
  const int l = threadIdx.x;
  const float* per = pe + (size_t)row*NONGT_*POS_;
  for (int i = l; i < NONGT_*POS_; i += 64) spe[(i >> 6)*68 + (i & 63)] = per[i];
  for (int i = l; i < POS_*H_; i += 64) swpT[(i & 7)*68 + (i >> 3)] = Wpos[i];
  if (l < H_) sbp[l] = bpos[l];
  __syncthreads();
  #pragma unroll
  for (int t = 0; t < 3; ++t) {
    int idx = t*64 + l;
    if (idx < NONGT_*H_) {
      int j = idx >> 3, h = idx & 7;
      float s = sbp[h];
      const float4* a4 = (const float4*)(spe + j*68);
      const float4* b4 = (const float4*)(swpT + h*68);
      #pragma unroll
      for (int p4 = 0; p4 < 16; ++p4) {
        float4 a = a4[p4], bv = b4[p4];
        s += a.x*bv.x + a.y*bv.y + a.z*bv.z + a.w*bv.w;
      }
      s = fmaxf(s, 0.f);
      posb[(size_t)row*160 + h*20 + j] = __logf(fmaxf(s, 1e-6f));
    }
  }
}

// ---------------- logits + softmax -> pbuf ----------------
__global__ __launch_bounds__(512, 1) void logits_kernel(
    const bf16* __restrict__ qbuf, const float* __restrict__ kbuf,
    const float* __restrict__ posb, const int* __restrict__ adj,
    const float* __restrict__ lb, float* __restrict__ pbuf)
{
  __shared__ __align__(16) bf16 sk[KPAD_*776];
  __shared__ __align__(16) bf16 sq[8*FEAT_];
  const int tid = threadIdx.x;
  const int w = tid >> 6, l = tid & 63;
  const int row0 = blockIdx.x * 8;
  const int b = row0 / N_;
  for (int i = tid; i < KPAD_*FEAT_/4; i += 512) {
    int j = (i << 2) / FEAT_, f = (i << 2) % FEAT_;
    float4 kv = *(const float4*)(kbuf + ((size_t)b*KPAD_ + j)*FEAT_ + f);
    uint2 u;
    u.x = (unsigned int)bfbits((bf16)kv.x) | ((unsigned int)bfbits((bf16)kv.y) << 16);
    u.y = (unsigned int)bfbits((bf16)kv.z) | ((unsigned int)bfbits((bf16)kv.w) << 16);
    *(uint2*)(sk + j*776 + f) = u;
  }
  for (int i = tid; i < 8*FEAT_/8; i += 512)
    ((bf16x8*)sq)[i] = *(const bf16x8*)(qbuf + (size_t)row0*FEAT_ + (size_t)i*8);
  __syncthreads();
  const size_t row = row0 + w;
  const int j = l & 31, hh = l >> 5;
  const int* adjr = adj + row*NONGT_;
  const float* lbr = lb + row*NONGT_;
  const float* pbr = posb + row*160;
  float lg[4];
  #pragma unroll
  for (int t = 0; t < 4; ++t) {
    const int h = t*2 + hh;
    const uint4* kp = (const uint4*)(sk + j*776 + h*DG_);
    const uint4* qp = (const uint4*)(sq + w*FEAT_ + h*DG_);
    float s = 0.f;
    #pragma unroll
    for (int d8 = 0; d8 < 12; ++d8)
      s += dot8(kp[d8], qp[d8]);
    float v = s * INV_SQRT_DG;
    if (j < NONGT_) {
      float pbv = pbr[h*20 + j];
      v = (adjr[j] > 0 ? v + pbv : NEG_) + lbr[j];
    } else if (j >= KTOT_) {
      v = -3.0e38f;
    }
    lg[t] = v;
  }
  float* prow = pbuf + row*(H_*KPAD_);
  #pragma unroll
  for (int t = 0; t < 4; ++t) {
    float m = lg[t];
    #pragma unroll
    for (int o = 16; o > 0; o >>= 1) m = fmaxf(m, __shfl_xor(m, o));
    float e = __expf(lg[t] - m);
    float ssum = e;
    #pragma unroll
    for (int o = 16; o > 0; o >>= 1) ssum += __shfl_xor(ssum, o);
    prow[(t*2 + hh)*KPAD_ + j] = e / ssum;
  }
}

// ---------------- out = p @ vw + bout ----------------
__global__ __launch_bounds__(512, 1) void pv_kernel(
    const float* __restrict__ pbuf, const float* __restrict__ vw,
    const float* __restrict__ bout, float* __restrict__ out)
{
  __shared__ __align__(16) float svw[KTOT_*388];
  __shared__ __align__(16) float sp[8*H_*KPAD_];
  const int tid = threadIdx.x;
  const int w = tid >> 6, l = tid & 63;
  const int row0 = blockIdx.y * 8;
  const int b = row0 / N_;
  const int cbase = blockIdx.x * 384;
  for (int i = tid; i < KTOT_*96; i += 512) {
    int j = i / 96, c4 = (i % 96) << 2;
    *(float4*)(svw + j*388 + c4) = *(const float4*)(vw + ((size_t)b*KPAD_ + j)*FEAT_ + cbase + c4);
  }
  for (int i = tid; i < 512; i += 512)
    ((float4*)sp)[i] = ((const float4*)(pbuf + (size_t)row0*(H_*KPAD_)))[i];
  __syncthreads();
  const size_t row = row0 + w;
  float* orow = out + row*FEAT_ + cbase;
  const float* sprow = sp + w*(H_*KPAD_);
  #pragma unroll
  for (int k3 = 0; k3 < 3; ++k3) {
    const int c = k3*128 + (l << 1);
    const int h0 = (cbase + c) / DG_;
    float s0 = 0.f, s1 = 0.f;
    #pragma unroll
    for (int jj = 0; jj < KTOT_; ++jj) {
      float2 vv = *(const float2*)(svw + jj*388 + c);
      s0 = fmaf(sprow[h0*KPAD_ + jj], vv.x, s0);
      s1 = fmaf(sprow[h0*KPAD_ + jj], vv.y, s1);
    }
    float2 o2;
    o2.x = s0 + bout[cbase + c];
    o2.y = s1 + bout[cbase + c + 1];
    *(float2*)(orow + c) = o2;
  }
}

extern "C" void kernel_launch(void* const* d_in, const int* in_sizes, int n_in,
                              void* d_out, int out_size, void* d_ws, size_t ws_size,
                              hipStream_t stream) {
  const float* roi  = (const float*)d_in[0];
  const int*   adj  = (const int*)  d_in[1];
  const float* pe   = (const float*)d_in[2];
  const float* lb   = (const float*)d_in[3];
  const float* aux  = (const float*)d_in[4];
  const float* Wq   = (const float*)d_in[5];
  const float* bq   = (const float*)d_in[6];
  const float* Wk   = (const float*)d_in[7];
  const float* bk   = (const float*)d_in[8];
  const float* Wpos = (const float*)d_in[9];
  const float* bpos = (const float*)d_in[10];
  const float* m_k  = (const float*)d_in[11];
  const float* m_v  = (const float*)d_in[12];
  const float* Wout = (const float*)d_in[13];
  const float* bout = (const float*)d_in[14];
  float* out = (float*)d_out;

  char* pw = (char*)d_ws;
  auto carve = [&](size_t bytes) -> void* {
    void* r = pw; pw += (bytes + 255) & ~(size_t)255; return r;
  };
  bf16*  Abf   = (bf16*) carve((size_t)ROWS_*FEAT_*2);
  bf16*  qbuf  = (bf16*) carve((size_t)ROWS_*FEAT_*2);
  bf16*  Wq_t  = (bf16*) carve((size_t)FEAT_*FEAT_*2);
  bf16*  Wk_t  = (bf16*) carve((size_t)FEAT_*FEAT_*2);
  bf16*  Whi   = (bf16*) carve((size_t)FEAT_*FEAT_*2);
  bf16*  Wlo   = (bf16*) carve((size_t)FEAT_*FEAT_*2);
  bf16*  Vbf   = (bf16*) carve((size_t)B_*KPAD_*FEAT_*2);
  float* kbuf  = (float*)carve((size_t)B_*KPAD_*FEAT_*4);
  float* vwbuf = (float*)carve((size_t)B_*KPAD_*FEAT_*4);
  float* pbuf  = (float*)carve((size_t)ROWS_*H_*KPAD_*4);
  float* posb  = (float*)carve((size_t)ROWS_*160*4);

  prep_kernel<<<dim3(1024), dim3(256), 0, stream>>>(Wq, Wk, Wout, roi, aux, m_v,
                                                    Wq_t, Wk_t, Whi, Wlo, Vbf);
  convert_roi_kernel<<<dim3(6144), dim3(256), 0, stream>>>(roi, Abf);
  posbias_kernel<<<dim3(16384), dim3(64), 0, stream>>>(pe, Wpos, bpos, posb);
  gemm128_kernel<<<dim3(6, 128), dim3(256), 0, stream>>>(Abf, Wq_t, bq, qbuf);
  gemm_small_kernel<<<dim3(6, 32), dim3(64), 0, stream>>>(Abf, Wk_t, (const bf16*)nullptr,
                                                          bk, kbuf, 1);
  fill_mk_kernel<<<dim3(480), dim3(256), 0, stream>>>(m_k, aux, kbuf);
  gemm_small_kernel<<<dim3(6, 32), dim3(64), 0, stream>>>(Vbf, Whi, Wlo,
                                                          (const float*)nullptr, vwbuf, 0);
  logits_kernel<<<dim3(2048), dim3(512), 0, stream>>>(qbuf, kbuf, posb, adj, lb, pbuf);
  pv_kernel<<<dim3(2, 2048), dim3(512), 0, stream>>>(pbuf, vwbuf, bout, out);
}

// Round 2
// 203.676 us; speedup vs baseline: 1.5519x; 1.5519x over previous
//
#include <hip/hip_runtime.h>
#include <hip/hip_bf16.h>
#include <cstdint>

typedef __bf16 bf16;
typedef __bf16 bf16x8 __attribute__((ext_vector_type(8)));
typedef float f32x4 __attribute__((ext_vector_type(4)));

#define B_ 16
#define N_ 1024
#define FEAT_ 768
#define H_ 8
#define NONGT_ 20
#define M_ 10
#define POS_ 64
#define DG_ 96
#define KTOT_ 30
#define KPAD_ 32
#define ROWS_ (B_*N_)
#define SCALE_M 9.797958971132712f
#define INV_SQRT_DG 0.10206207261596575f
#define NEG_ -9.0e15f

__device__ __forceinline__ void gload16(const void* g, void* lds) {
  __builtin_amdgcn_global_load_lds(
      (const __attribute__((address_space(1))) unsigned int*)g,
      (__attribute__((address_space(3))) unsigned int*)lds, 16, 0, 0);
}

__device__ __forceinline__ unsigned short bfbits(bf16 x) {
  union { bf16 b; unsigned short u; } c; c.b = x; return c.u;
}
__device__ __forceinline__ float bflo(unsigned int u) { return __uint_as_float(u << 16); }
__device__ __forceinline__ float bfhi(unsigned int u) { return __uint_as_float(u & 0xffff0000u); }
__device__ __forceinline__ float dot8(uint4 a, uint4 b) {
  float s = bflo(a.x)*bflo(b.x) + bfhi(a.x)*bfhi(b.x);
  s += bflo(a.y)*bflo(b.y) + bfhi(a.y)*bfhi(b.y);
  s += bflo(a.z)*bflo(b.z) + bfhi(a.z)*bfhi(b.z);
  s += bflo(a.w)*bflo(b.w) + bfhi(a.w)*bfhi(b.w);
  return s;
}

// ---------------- prep: weight transposes/conversions + V build ----------------
__global__ void prep_kernel(const float* __restrict__ Wq, const float* __restrict__ Wk,
                            const float* __restrict__ Wout, const float* __restrict__ roi,
                            const float* __restrict__ aux, const float* __restrict__ m_v,
                            bf16* __restrict__ Wq_t, bf16* __restrict__ Wk_t,
                            bf16* __restrict__ Whi, bf16* __restrict__ Wlo,
                            bf16* __restrict__ Vbf)
{
  int idx = blockIdx.x * blockDim.x + threadIdx.x;
  int stride = gridDim.x * blockDim.x;
  for (int i = idx; i < FEAT_*FEAT_; i += stride) {
    int n = i / FEAT_, k = i % FEAT_;
    Wq_t[i] = (bf16)Wq[k*FEAT_ + n];
    Wk_t[i] = (bf16)Wk[k*FEAT_ + n];
    float w = Wout[i];              // Wout is [(h*DG+g)][f] row-major already
    bf16 hi = (bf16)w;
    Whi[i] = hi;
    Wlo[i] = (bf16)(w - (float)hi);
  }
  for (int i = idx; i < B_*KPAD_*FEAT_; i += stride) {
    int f = i % FEAT_;
    int r = (i / FEAT_) % KPAD_;
    int b = i / (FEAT_*KPAD_);
    float v;
    if (r < NONGT_)      v = roi[((size_t)b*N_ + r)*FEAT_ + f];
    else if (r < KTOT_)  v = SCALE_M * m_v[(r-NONGT_)*FEAT_ + f] * aux[b*FEAT_ + f];
    else                 v = 0.f;
    Vbf[i] = (bf16)v;
  }
}

// ---------------- roi -> bf16 ----------------
__global__ void convert_roi_kernel(const float* __restrict__ roi, bf16* __restrict__ Abf) {
  int idx = blockIdx.x * blockDim.x + threadIdx.x;
  const int total8 = ROWS_*FEAT_/8;
  int stride = gridDim.x * blockDim.x;
  for (int i = idx; i < total8; i += stride) {
    const float4* p = (const float4*)(roi + (size_t)i*8);
    float4 x = p[0], y = p[1];
    bf16x8 o;
    o[0]=(bf16)x.x; o[1]=(bf16)x.y; o[2]=(bf16)x.z; o[3]=(bf16)x.w;
    o[4]=(bf16)y.x; o[5]=(bf16)y.y; o[6]=(bf16)y.z; o[7]=(bf16)y.w;
    *(bf16x8*)(Abf + (size_t)i*8) = o;
  }
}

// ---------------- 128x128 bf16 MFMA GEMM: C = A @ Bm^T + bias (bf16 out) ----------------
__global__ __launch_bounds__(256, 2) void gemm128_kernel(
    const bf16* __restrict__ A, const bf16* __restrict__ Bm,
    const float* __restrict__ bias, bf16* __restrict__ C)
{
  __shared__ __align__(16) bf16 sA[128*32];
  __shared__ __align__(16) bf16 sB[128*32];
  const int tid = threadIdx.x;
  const int w = tid >> 6, l = tid & 63;
  const int mbase = blockIdx.y * 128;
  const int nbase = blockIdx.x * 128;
  const int wr = w >> 1, wc = w & 1;
  const int srow = tid >> 2;
  const int scol = (tid & 3) << 3;
  const bf16* Ag0 = A + (size_t)(mbase + srow)*FEAT_ + scol;
  const bf16* Ag1 = Ag0 + (size_t)64*FEAT_;
  const bf16* Bg0 = Bm + (size_t)(nbase + srow)*FEAT_ + scol;
  const bf16* Bg1 = Bg0 + (size_t)64*FEAT_;
  bf16* ldsA0 = sA + w*512;
  bf16* ldsA1 = sA + 2048 + w*512;
  bf16* ldsB0 = sB + w*512;
  bf16* ldsB1 = sB + 2048 + w*512;
  const int fr = l & 15, fko = (l >> 4) << 3;
  f32x4 acc[4][4] = {};
  for (int kt = 0; kt < FEAT_/32; ++kt) {
    __syncthreads();
    gload16(Ag0 + kt*32, ldsA0);
    gload16(Ag1 + kt*32, ldsA1);
    gload16(Bg0 + kt*32, ldsB0);
    gload16(Bg1 + kt*32, ldsB1);
    __syncthreads();
    bf16x8 af[4], bff[4];
    #pragma unroll
    for (int m = 0; m < 4; ++m)
      af[m] = *(const bf16x8*)(sA + (wr*64 + m*16 + fr)*32 + fko);
    #pragma unroll
    for (int n = 0; n < 4; ++n)
      bff[n] = *(const bf16x8*)(sB + (wc*64 + n*16 + fr)*32 + fko);
    #pragma unroll
    for (int m = 0; m < 4; ++m) {
      #pragma unroll
      for (int n = 0; n < 4; ++n)
        acc[m][n] = __builtin_amdgcn_mfma_f32_16x16x32_bf16(af[m], bff[n], acc[m][n], 0, 0, 0);
    }
  }
  const int fq = l >> 4;
  #pragma unroll
  for (int n = 0; n < 4; ++n) {
    const int col = nbase + wc*64 + n*16 + fr;
    const float bv = bias[col];
    #pragma unroll
    for (int m = 0; m < 4; ++m) {
      const int row = mbase + wr*64 + m*16 + fq*4;
      #pragma unroll
      for (int r = 0; r < 4; ++r)
        C[(size_t)(row + r)*FEAT_ + col] = (bf16)(acc[m][n][r] + bv);
    }
  }
}

// ---------------- fused small GEMMs: one wave per 16x16 output tile ----------------
// by < 32  : K-GEMM   kbuf[b*KPAD + t*16 + ...] = Abf(rows of roi) @ Wk_t^T + bk  (bf16 out)
// by >= 32 : VW-GEMM  vwbuf[row] = Vbf @ (Whi^T + Wlo^T)                           (f32 out)
__global__ __launch_bounds__(64, 8) void gemm_small2_kernel(
    const bf16* __restrict__ Abf, const bf16* __restrict__ Wk_t,
    const bf16* __restrict__ Vbf, const bf16* __restrict__ Whi, const bf16* __restrict__ Wlo,
    const float* __restrict__ bk, bf16* __restrict__ kbuf, float* __restrict__ vwbuf)
{
  const int l = threadIdx.x;
  const int fr = l & 15, fko = (l >> 4) << 3, fq = l >> 4;
  const int cbase = blockIdx.x * 16;
  const int by = blockIdx.y;
  f32x4 acc = {};
  if (by < 32) {
    const bf16* Ap = Abf + ((size_t)(by >> 1)*N_ + (by & 1)*16 + fr)*FEAT_ + fko;
    const bf16* Bp = Wk_t + (size_t)(cbase + fr)*FEAT_ + fko;
    #pragma unroll
    for (int kt = 0; kt < FEAT_/32; ++kt) {
      bf16x8 a = *(const bf16x8*)(Ap + kt*32);
      bf16x8 b = *(const bf16x8*)(Bp + kt*32);
      acc = __builtin_amdgcn_mfma_f32_16x16x32_bf16(a, b, acc, 0, 0, 0);
    }
    const float bv = bk[cbase + fr];
    const int rbase = (by >> 1)*KPAD_ + (by & 1)*16 + fq*4;
    #pragma unroll
    for (int r = 0; r < 4; ++r)
      kbuf[(size_t)(rbase + r)*FEAT_ + cbase + fr] = (bf16)(acc[r] + bv);
  } else {
    const int rt = by - 32;
    const bf16* Ap = Vbf + ((size_t)rt*16 + fr)*FEAT_ + fko;
    const bf16* B1 = Whi + (size_t)(cbase + fr)*FEAT_ + fko;
    const bf16* B2 = Wlo + (size_t)(cbase + fr)*FEAT_ + fko;
    f32x4 acc2 = {};
    #pragma unroll
    for (int kt = 0; kt < FEAT_/32; ++kt) {
      bf16x8 a = *(const bf16x8*)(Ap + kt*32);
      acc  = __builtin_amdgcn_mfma_f32_16x16x32_bf16(a, *(const bf16x8*)(B1 + kt*32), acc,  0, 0, 0);
      acc2 = __builtin_amdgcn_mfma_f32_16x16x32_bf16(a, *(const bf16x8*)(B2 + kt*32), acc2, 0, 0, 0);
    }
    const int rbase = rt*16 + fq*4;
    #pragma unroll
    for (int r = 0; r < 4; ++r)
      vwbuf[(size_t)(rbase + r)*FEAT_ + cbase + fr] = acc[r] + acc2[r];
  }
}

// ---------------- position bias: log(max(relu(pe@Wpos+bpos),1e-6)) ----------------
__global__ __launch_bounds__(64, 4) void posbias_kernel(
    const float* __restrict__ pe, const float* __restrict__ Wpos,
    const float* __restrict__ bpos, float* __restrict__ posb)
{
  __shared__ __align__(16) float spe[NONGT_*68];
  __shared__ __align__(16) float swpT[H_*68];
  __shared__ float sbp[H_];
  const int row = blockIdx.x;
  const int l = threadIdx.x;
  const float* per = pe + (size_t)row*NONGT_*POS_;
  for (int i = l; i < NONGT_*POS_; i += 64) spe[(i >> 6)*68 + (i & 63)] = per[i];
  for (int i = l; i < POS_*H_; i += 64) swpT[(i & 7)*68 + (i >> 3)] = Wpos[i];
  if (l < H_) sbp[l] = bpos[l];
  __syncthreads();
  #pragma unroll
  for (int t = 0; t < 3; ++t) {
    int idx = t*64 + l;
    if (idx < NONGT_*H_) {
      int j = idx >> 3, h = idx & 7;
      float s = sbp[h];
      const float4* a4 = (const float4*)(spe + j*68);
      const float4* b4 = (const float4*)(swpT + h*68);
      #pragma unroll
      for (int p4 = 0; p4 < 16; ++p4) {
        float4 a = a4[p4], bv = b4[p4];
        s += a.x*bv.x + a.y*bv.y + a.z*bv.z + a.w*bv.w;
      }
      s = fmaxf(s, 0.f);
      posb[(size_t)row*160 + h*20 + j] = __logf(fmaxf(s, 1e-6f));
    }
  }
}

// ---------------- logits + softmax -> pbuf (mk rows computed inline) ----------------
__global__ __launch_bounds__(512, 1) void logits_kernel(
    const bf16* __restrict__ qbuf, const bf16* __restrict__ kbuf,
    const float* __restrict__ m_k, const float* __restrict__ aux,
    const float* __restrict__ posb, const int* __restrict__ adj,
    const float* __restrict__ lb, float* __restrict__ pbuf)
{
  __shared__ __align__(16) bf16 sk[KPAD_*776];
  __shared__ __align__(16) bf16 sq[8*FEAT_];
  const int tid = threadIdx.x;
  const int w = tid >> 6, l = tid & 63;
  const int row0 = blockIdx.x * 8;
  const int b = row0 / N_;
  for (int i = tid; i < KPAD_*FEAT_/8; i += 512) {
    int j = i / (FEAT_/8);
    int f = (i % (FEAT_/8)) * 8;
    bf16x8 kv;
    if (j < NONGT_) {
      kv = *(const bf16x8*)(kbuf + ((size_t)b*KPAD_ + j)*FEAT_ + f);
    } else if (j < KTOT_) {
      const float* mkp = m_k + (j - NONGT_)*FEAT_ + f;
      const float* axp = aux + b*FEAT_ + f;
      #pragma unroll
      for (int e = 0; e < 8; ++e) kv[e] = (bf16)(SCALE_M * mkp[e] * axp[e]);
    } else {
      #pragma unroll
      for (int e = 0; e < 8; ++e) kv[e] = (bf16)0.f;
    }
    *(bf16x8*)(sk + j*776 + f) = kv;
  }
  for (int i = tid; i < 8*FEAT_/8; i += 512)
    ((bf16x8*)sq)[i] = *(const bf16x8*)(qbuf + (size_t)row0*FEAT_ + (size_t)i*8);
  __syncthreads();
  const size_t row = row0 + w;
  const int j = l & 31, hh = l >> 5;
  const int* adjr = adj + row*NONGT_;
  const float* lbr = lb + row*NONGT_;
  const float* pbr = posb + row*160;
  float lg[4];
  #pragma unroll
  for (int t = 0; t < 4; ++t) {
    const int h = t*2 + hh;
    const uint4* kp = (const uint4*)(sk + j*776 + h*DG_);
    const uint4* qp = (const uint4*)(sq + w*FEAT_ + h*DG_);
    float s = 0.f;
    #pragma unroll
    for (int d8 = 0; d8 < 12; ++d8)
      s += dot8(kp[d8], qp[d8]);
    float v = s * INV_SQRT_DG;
    if (j < NONGT_) {
      float pbv = pbr[h*20 + j];
      v = (adjr[j] > 0 ? v + pbv : NEG_) + lbr[j];
    } else if (j >= KTOT_) {
      v = -3.0e38f;
    }
    lg[t] = v;
  }
  float* prow = pbuf + row*(H_*KPAD_);
  #pragma unroll
  for (int t = 0; t < 4; ++t) {
    float m = lg[t];
    #pragma unroll
    for (int o = 16; o > 0; o >>= 1) m = fmaxf(m, __shfl_xor(m, o));
    float e = __expf(lg[t] - m);
    float ssum = e;
    #pragma unroll
    for (int o = 16; o > 0; o >>= 1) ssum += __shfl_xor(ssum, o);
    prow[(t*2 + hh)*KPAD_ + j] = e / ssum;
  }
}

// ---------------- out = p @ vw + bout ----------------
__global__ __launch_bounds__(512, 1) void pv_kernel(
    const float* __restrict__ pbuf, const float* __restrict__ vw,
    const float* __restrict__ bout, float* __restrict__ out)
{
  __shared__ __align__(16) float svw[KTOT_*388];
  __shared__ __align__(16) float sp[8*H_*KPAD_];
  const int tid = threadIdx.x;
  const int w = tid >> 6, l = tid & 63;
  const int row0 = blockIdx.y * 8;
  const int b = row0 / N_;
  const int cbase = blockIdx.x * 384;
  for (int i = tid; i < KTOT_*96; i += 512) {
    int j = i / 96, c4 = (i % 96) << 2;
    *(float4*)(svw + j*388 + c4) = *(const float4*)(vw + ((size_t)b*KPAD_ + j)*FEAT_ + cbase + c4);
  }
  for (int i = tid; i < 512; i += 512)
    ((float4*)sp)[i] = ((const float4*)(pbuf + (size_t)row0*(H_*KPAD_)))[i];
  __syncthreads();
  const size_t row = row0 + w;
  float* orow = out + row*FEAT_ + cbase;
  const float* sprow = sp + w*(H_*KPAD_);
  #pragma unroll
  for (int k3 = 0; k3 < 3; ++k3) {
    const int c = k3*128 + (l << 1);
    const int h0 = (cbase + c) / DG_;
    float s0 = 0.f, s1 = 0.f;
    #pragma unroll
    for (int jj = 0; jj < KTOT_; ++jj) {
      float2 vv = *(const float2*)(svw + jj*388 + c);
      s0 = fmaf(sprow[h0*KPAD_ + jj], vv.x, s0);
      s1 = fmaf(sprow[h0*KPAD_ + jj], vv.y, s1);
    }
    float2 o2;
    o2.x = s0 + bout[cbase + c];
    o2.y = s1 + bout[cbase + c + 1];
    *(float2*)(orow + c) = o2;
  }
}

extern "C" void kernel_launch(void* const* d_in, const int* in_sizes, int n_in,
                              void* d_out, int out_size, void* d_ws, size_t ws_size,
                              hipStream_t stream) {
  const float* roi  = (const float*)d_in[0];
  const int*   adj  = (const int*)  d_in[1];
  const float* pe   = (const float*)d_in[2];
  const float* lb   = (const float*)d_in[3];
  const float* aux  = (const float*)d_in[4];
  const float* Wq   = (const float*)d_in[5];
  const float* bq   = (const float*)d_in[6];
  const float* Wk   = (const float*)d_in[7];
  const float* bk   = (const float*)d_in[8];
  const float* Wpos = (const float*)d_in[9];
  const float* bpos = (const float*)d_in[10];
  const float* m_k  = (const float*)d_in[11];
  const float* m_v  = (const float*)d_in[12];
  const float* Wout = (const float*)d_in[13];
  const float* bout = (const float*)d_in[14];
  float* out = (float*)d_out;

  char* pw = (char*)d_ws;
  auto carve = [&](size_t bytes) -> void* {
    void* r = pw; pw += (bytes + 255) & ~(size_t)255; return r;
  };
  bf16*  Abf   = (bf16*) carve((size_t)ROWS_*FEAT_*2);
  bf16*  qbuf  = (bf16*) carve((size_t)ROWS_*FEAT_*2);
  bf16*  Wq_t  = (bf16*) carve((size_t)FEAT_*FEAT_*2);
  bf16*  Wk_t  = (bf16*) carve((size_t)FEAT_*FEAT_*2);
  bf16*  Whi   = (bf16*) carve((size_t)FEAT_*FEAT_*2);
  bf16*  Wlo   = (bf16*) carve((size_t)FEAT_*FEAT_*2);
  bf16*  Vbf   = (bf16*) carve((size_t)B_*KPAD_*FEAT_*2);
  bf16*  kbuf  = (bf16*) carve((size_t)B_*KPAD_*FEAT_*2);
  float* vwbuf = (float*)carve((size_t)B_*KPAD_*FEAT_*4);
  float* pbuf  = (float*)carve((size_t)ROWS_*H_*KPAD_*4);
  float* posb  = (float*)carve((size_t)ROWS_*160*4);

  prep_kernel<<<dim3(1024), dim3(256), 0, stream>>>(Wq, Wk, Wout, roi, aux, m_v,
                                                    Wq_t, Wk_t, Whi, Wlo, Vbf);
  convert_roi_kernel<<<dim3(6144), dim3(256), 0, stream>>>(roi, Abf);
  posbias_kernel<<<dim3(16384), dim3(64), 0, stream>>>(pe, Wpos, bpos, posb);
  gemm128_kernel<<<dim3(6, 128), dim3(256), 0, stream>>>(Abf, Wq_t, bq, qbuf);
  gemm_small2_kernel<<<dim3(48, 64), dim3(64), 0, stream>>>(Abf, Wk_t, Vbf, Whi, Wlo,
                                                            bk, kbuf, vwbuf);
  logits_kernel<<<dim3(2048), dim3(512), 0, stream>>>(qbuf, kbuf, m_k, aux, posb, adj, lb, pbuf);
  pv_kernel<<<dim3(2, 2048), dim3(512), 0, stream>>>(pbuf, vwbuf, bout, out);
}

// Round 3
// 138.288 us; speedup vs baseline: 2.2857x; 1.4728x over previous
//
#include <hip/hip_runtime.h>
#include <hip/hip_bf16.h>
#include <cstdint>

typedef __bf16 bf16;
typedef __bf16 bf16x4 __attribute__((ext_vector_type(4)));
typedef __bf16 bf16x8 __attribute__((ext_vector_type(8)));
typedef float f32x4 __attribute__((ext_vector_type(4)));

#define B_ 16
#define N_ 1024
#define FEAT_ 768
#define H_ 8
#define NONGT_ 20
#define M_ 10
#define POS_ 64
#define DG_ 96
#define KTOT_ 30
#define KPAD_ 32
#define ROWS_ (B_*N_)
#define SCALE_M 9.797958971132712f
#define INV_SQRT_DG 0.10206207261596575f
#define NEG_ -9.0e15f

__device__ __forceinline__ void gload16(const void* g, void* lds) {
  __builtin_amdgcn_global_load_lds(
      (const __attribute__((address_space(1))) unsigned int*)g,
      (__attribute__((address_space(3))) unsigned int*)lds, 16, 0, 0);
}

// ---------------- prep: weight transposes/conversions + V build + mk rows of kbuf ----
__global__ void prep_kernel(const float* __restrict__ Wq, const float* __restrict__ Wk,
                            const float* __restrict__ Wout, const float* __restrict__ roi,
                            const float* __restrict__ aux, const float* __restrict__ m_v,
                            const float* __restrict__ m_k,
                            bf16* __restrict__ Wq_t, bf16* __restrict__ Wk_t,
                            bf16* __restrict__ Whi, bf16* __restrict__ Wlo,
                            bf16* __restrict__ Vbf, bf16* __restrict__ kbuf)
{
  int idx = blockIdx.x * blockDim.x + threadIdx.x;
  int stride = gridDim.x * blockDim.x;
  for (int i = idx; i < FEAT_*FEAT_; i += stride) {
    int n = i / FEAT_, k = i % FEAT_;
    Wq_t[i] = (bf16)Wq[k*FEAT_ + n];
    Wk_t[i] = (bf16)Wk[k*FEAT_ + n];
    float w = Wout[i];              // Wout is [(h*DG+g)][f] row-major already
    bf16 hi = (bf16)w;
    Whi[i] = hi;
    Wlo[i] = (bf16)(w - (float)hi);
  }
  for (int i = idx; i < B_*KPAD_*FEAT_; i += stride) {
    int f = i % FEAT_;
    int r = (i / FEAT_) % KPAD_;
    int b = i / (FEAT_*KPAD_);
    float v;
    if (r < NONGT_)      v = roi[((size_t)b*N_ + r)*FEAT_ + f];
    else if (r < KTOT_)  v = SCALE_M * m_v[(r-NONGT_)*FEAT_ + f] * aux[b*FEAT_ + f];
    else                 v = 0.f;
    Vbf[i] = (bf16)v;
  }
  // kbuf rows 20..31 (mk keys + zero pad); rows 0..19 written by gemm_small2
  for (int i = idx; i < B_*12*FEAT_; i += stride) {
    int f = i % FEAT_;
    int rr = (i / FEAT_) % 12;
    int b = i / (FEAT_*12);
    float v = (rr < M_) ? SCALE_M * m_k[rr*FEAT_ + f] * aux[b*FEAT_ + f] : 0.f;
    kbuf[((size_t)b*KPAD_ + NONGT_ + rr)*FEAT_ + f] = (bf16)v;
  }
}

// ---------------- roi -> bf16 ----------------
__global__ void convert_roi_kernel(const float* __restrict__ roi, bf16* __restrict__ Abf) {
  int idx = blockIdx.x * blockDim.x + threadIdx.x;
  const int total8 = ROWS_*FEAT_/8;
  int stride = gridDim.x * blockDim.x;
  for (int i = idx; i < total8; i += stride) {
    const float4* p = (const float4*)(roi + (size_t)i*8);
    float4 x = p[0], y = p[1];
    bf16x8 o;
    o[0]=(bf16)x.x; o[1]=(bf16)x.y; o[2]=(bf16)x.z; o[3]=(bf16)x.w;
    o[4]=(bf16)y.x; o[5]=(bf16)y.y; o[6]=(bf16)y.z; o[7]=(bf16)y.w;
    *(bf16x8*)(Abf + (size_t)i*8) = o;
  }
}

// ---------------- 128x128 bf16 MFMA GEMM: C = A @ Bm^T + bias (bf16 out) ----------------
__global__ __launch_bounds__(256, 2) void gemm128_kernel(
    const bf16* __restrict__ A, const bf16* __restrict__ Bm,
    const float* __restrict__ bias, bf16* __restrict__ C)
{
  __shared__ __align__(16) bf16 sA[128*32];
  __shared__ __align__(16) bf16 sB[128*32];
  const int tid = threadIdx.x;
  const int w = tid >> 6, l = tid & 63;
  const int mbase = blockIdx.y * 128;
  const int nbase = blockIdx.x * 128;
  const int wr = w >> 1, wc = w & 1;
  const int srow = tid >> 2;
  const int scol = (tid & 3) << 3;
  const bf16* Ag0 = A + (size_t)(mbase + srow)*FEAT_ + scol;
  const bf16* Ag1 = Ag0 + (size_t)64*FEAT_;
  const bf16* Bg0 = Bm + (size_t)(nbase + srow)*FEAT_ + scol;
  const bf16* Bg1 = Bg0 + (size_t)64*FEAT_;
  bf16* ldsA0 = sA + w*512;
  bf16* ldsA1 = sA + 2048 + w*512;
  bf16* ldsB0 = sB + w*512;
  bf16* ldsB1 = sB + 2048 + w*512;
  const int fr = l & 15, fko = (l >> 4) << 3;
  f32x4 acc[4][4] = {};
  for (int kt = 0; kt < FEAT_/32; ++kt) {
    __syncthreads();
    gload16(Ag0 + kt*32, ldsA0);
    gload16(Ag1 + kt*32, ldsA1);
    gload16(Bg0 + kt*32, ldsB0);
    gload16(Bg1 + kt*32, ldsB1);
    __syncthreads();
    bf16x8 af[4], bff[4];
    #pragma unroll
    for (int m = 0; m < 4; ++m)
      af[m] = *(const bf16x8*)(sA + (wr*64 + m*16 + fr)*32 + fko);
    #pragma unroll
    for (int n = 0; n < 4; ++n)
      bff[n] = *(const bf16x8*)(sB + (wc*64 + n*16 + fr)*32 + fko);
    #pragma unroll
    for (int m = 0; m < 4; ++m) {
      #pragma unroll
      for (int n = 0; n < 4; ++n)
        acc[m][n] = __builtin_amdgcn_mfma_f32_16x16x32_bf16(af[m], bff[n], acc[m][n], 0, 0, 0);
    }
  }
  const int fq = l >> 4;
  #pragma unroll
  for (int n = 0; n < 4; ++n) {
    const int col = nbase + wc*64 + n*16 + fr;
    const float bv = bias[col];
    #pragma unroll
    for (int m = 0; m < 4; ++m) {
      const int row = mbase + wr*64 + m*16 + fq*4;
      #pragma unroll
      for (int r = 0; r < 4; ++r)
        C[(size_t)(row + r)*FEAT_ + col] = (bf16)(acc[m][n][r] + bv);
    }
  }
}

// ---------------- fused small GEMMs: one wave per 16x16 output tile ----------------
// by < 32  : K-GEMM   kbuf rows 0..19 per batch = roi_nongt @ Wk^T + bk  (bf16 out)
// by >= 32 : VW-GEMM  vwT[b][col][key] (hi/lo bf16) = (Vbf @ (Whi+Wlo)^T) transposed
__global__ __launch_bounds__(64, 8) void gemm_small2_kernel(
    const bf16* __restrict__ Abf, const bf16* __restrict__ Wk_t,
    const bf16* __restrict__ Vbf, const bf16* __restrict__ Whi, const bf16* __restrict__ Wlo,
    const float* __restrict__ bk, bf16* __restrict__ kbuf,
    bf16* __restrict__ vwT_hi, bf16* __restrict__ vwT_lo)
{
  const int l = threadIdx.x;
  const int fr = l & 15, fko = (l >> 4) << 3, fq = l >> 4;
  const int cbase = blockIdx.x * 16;
  const int by = blockIdx.y;
  f32x4 acc = {};
  if (by < 32) {
    const bf16* Ap = Abf + ((size_t)(by >> 1)*N_ + (by & 1)*16 + fr)*FEAT_ + fko;
    const bf16* Bp = Wk_t + (size_t)(cbase + fr)*FEAT_ + fko;
    #pragma unroll
    for (int kt = 0; kt < FEAT_/32; ++kt) {
      bf16x8 a = *(const bf16x8*)(Ap + kt*32);
      bf16x8 b = *(const bf16x8*)(Bp + kt*32);
      acc = __builtin_amdgcn_mfma_f32_16x16x32_bf16(a, b, acc, 0, 0, 0);
    }
    const float bv = bk[cbase + fr];
    #pragma unroll
    for (int r = 0; r < 4; ++r) {
      const int rl = (by & 1)*16 + fq*4 + r;       // local key row 0..31
      if (rl < NONGT_)
        kbuf[((size_t)(by >> 1)*KPAD_ + rl)*FEAT_ + cbase + fr] = (bf16)(acc[r] + bv);
    }
  } else {
    const int rt = by - 32;
    const bf16* Ap = Vbf + ((size_t)rt*16 + fr)*FEAT_ + fko;
    const bf16* B1 = Whi + (size_t)(cbase + fr)*FEAT_ + fko;
    const bf16* B2 = Wlo + (size_t)(cbase + fr)*FEAT_ + fko;
    f32x4 acc2 = {};
    #pragma unroll
    for (int kt = 0; kt < FEAT_/32; ++kt) {
      bf16x8 a = *(const bf16x8*)(Ap + kt*32);
      acc  = __builtin_amdgcn_mfma_f32_16x16x32_bf16(a, *(const bf16x8*)(B1 + kt*32), acc,  0, 0, 0);
      acc2 = __builtin_amdgcn_mfma_f32_16x16x32_bf16(a, *(const bf16x8*)(B2 + kt*32), acc2, 0, 0, 0);
    }
    #pragma unroll
    for (int r = 0; r < 4; ++r) {
      const int grow = rt*16 + fq*4 + r;           // 0..511
      const int b = grow >> 5, key = grow & 31;
      float vv = acc[r] + acc2[r];
      bf16 vh = (bf16)vv;
      size_t addr = ((size_t)b*FEAT_ + cbase + fr)*KPAD_ + key;
      vwT_hi[addr] = vh;
      vwT_lo[addr] = (bf16)(vv - (float)vh);
    }
  }
}

// ---------------- position bias: log(max(relu(pe@Wpos+bpos),1e-6)) ----------------
__global__ __launch_bounds__(64, 4) void posbias_kernel(
    const float* __restrict__ pe, const float* __restrict__ Wpos,
    const float* __restrict__ bpos, float* __restrict__ posb)
{
  __shared__ __align__(16) float spe[NONGT_*68];
  __shared__ __align__(16) float swpT[H_*68];
  __shared__ float sbp[H_];
  const int row = blockIdx.x;
  const int l = threadIdx.x;
  const float* per = pe + (size_t)row*NONGT_*POS_;
  for (int i = l; i < NONGT_*POS_; i += 64) spe[(i >> 6)*68 + (i & 63)] = per[i];
  for (int i = l; i < POS_*H_; i += 64) swpT[(i & 7)*68 + (i >> 3)] = Wpos[i];
  if (l < H_) sbp[l] = bpos[l];
  __syncthreads();
  #pragma unroll
  for (int t = 0; t < 3; ++t) {
    int idx = t*64 + l;
    if (idx < NONGT_*H_) {
      int j = idx >> 3, h = idx & 7;
      float s = sbp[h];
      const float4* a4 = (const float4*)(spe + j*68);
      const float4* b4 = (const float4*)(swpT + h*68);
      #pragma unroll
      for (int p4 = 0; p4 < 16; ++p4) {
        float4 a = a4[p4], bv = b4[p4];
        s += a.x*bv.x + a.y*bv.y + a.z*bv.z + a.w*bv.w;
      }
      s = fmaxf(s, 0.f);
      posb[(size_t)row*160 + h*20 + j] = __logf(fmaxf(s, 1e-6f));
    }
  }
}

// ---------------- fused attention: QK^T (MFMA) + softmax + PV (MFMA) ----------------
// grid (ntile=64, b=16), 256 threads = 4 waves; wave w owns heads 2w, 2w+1.
__global__ __launch_bounds__(256, 4) void attn_kernel(
    const bf16* __restrict__ qbuf, const bf16* __restrict__ kbuf,
    const bf16* __restrict__ vwT_hi, const bf16* __restrict__ vwT_lo,
    const float* __restrict__ posb, const int* __restrict__ adj,
    const float* __restrict__ lb, const float* __restrict__ bout,
    float* __restrict__ out)
{
  __shared__ __align__(16) bf16 sph[H_*16*40];   // p hi, padded key stride 40
  __shared__ __align__(16) bf16 spl[H_*16*40];   // p lo
  const int tid = threadIdx.x;
  const int w = tid >> 6, l = tid & 63;
  const int fr = l & 15, fq = l >> 4, fko = fq << 3;
  const int row0 = blockIdx.x * 16;
  const int b = blockIdx.y;
  const size_t rabs = (size_t)b*N_ + row0 + fr;   // this lane's q-row (for q/posb/adj/lb)

  #pragma unroll
  for (int hi2 = 0; hi2 < 2; ++hi2) {
    const int h = w*2 + hi2;
    // ---- QK^T: C[key][qrow], 2 key-tiles, K=96 ----
    const bf16* kp = kbuf + (size_t)b*KPAD_*FEAT_ + h*DG_ + fko;
    const bf16* qp = qbuf + rabs*FEAT_ + h*DG_ + fko;
    f32x4 acc0 = {}, acc1 = {};
    #pragma unroll
    for (int kt = 0; kt < 3; ++kt) {
      bf16x8 qa = *(const bf16x8*)(qp + kt*32);
      bf16x8 k0 = *(const bf16x8*)(kp + (size_t)fr*FEAT_ + kt*32);
      bf16x8 k1 = *(const bf16x8*)(kp + (size_t)(16 + fr)*FEAT_ + kt*32);
      acc0 = __builtin_amdgcn_mfma_f32_16x16x32_bf16(k0, qa, acc0, 0, 0, 0);
      acc1 = __builtin_amdgcn_mfma_f32_16x16x32_bf16(k1, qa, acc1, 0, 0, 0);
    }
    // ---- bias + mask; lane holds keys {fq*4+r, 16+fq*4+r} of q-row (row0+fr) ----
    const float* pbr = posb + rabs*160 + h*20;
    const int*   adjr = adj + rabs*20;
    const float* lbr  = lb  + rabs*20;
    float lg[2][4];
    #pragma unroll
    for (int r = 0; r < 4; ++r) {
      int j0 = fq*4 + r;          // < 20 always except fq=3? fq*4+r max 15 -> tile0 all <16<20
      float v0 = acc0[r] * INV_SQRT_DG;
      v0 = (adjr[j0] > 0 ? v0 + pbr[j0] : NEG_) + lbr[j0];
      lg[0][r] = v0;
      int j1 = 16 + fq*4 + r;
      float v1 = acc1[r] * INV_SQRT_DG;
      if (j1 < NONGT_)      v1 = (adjr[j1] > 0 ? v1 + pbr[j1] : NEG_) + lbr[j1];
      else if (j1 >= KTOT_) v1 = -3.0e38f;
      lg[1][r] = v1;
    }
    // ---- softmax over 32 keys: 8 regs x 4 lanes (fq) ----
    float m = lg[0][0];
    #pragma unroll
    for (int jt = 0; jt < 2; ++jt)
      #pragma unroll
      for (int r = 0; r < 4; ++r) m = fmaxf(m, lg[jt][r]);
    m = fmaxf(m, __shfl_xor(m, 16));
    m = fmaxf(m, __shfl_xor(m, 32));
    float s = 0.f;
    float e[2][4];
    #pragma unroll
    for (int jt = 0; jt < 2; ++jt)
      #pragma unroll
      for (int r = 0; r < 4; ++r) { e[jt][r] = __expf(lg[jt][r] - m); s += e[jt][r]; }
    s += __shfl_xor(s, 16);
    s += __shfl_xor(s, 32);
    const float inv = 1.f / s;
    // ---- p -> hi/lo bf16 -> LDS (wave-private region, no barrier) ----
    #pragma unroll
    for (int jt = 0; jt < 2; ++jt) {
      bf16x4 ph, pl;
      #pragma unroll
      for (int r = 0; r < 4; ++r) {
        float p = e[jt][r] * inv;
        ph[r] = (bf16)p;
        pl[r] = (bf16)(p - (float)ph[r]);
      }
      const int off = (h*16 + fr)*40 + jt*16 + fq*4;
      *(bf16x4*)(sph + off) = ph;
      *(bf16x4*)(spl + off) = pl;
    }
    // ---- PV: out[16 rows x 96 cols] via 6 col-tiles, K=32 (1 k-step), 3 passes ----
    bf16x8 pa_h = *(const bf16x8*)(sph + (h*16 + fr)*40 + fko);
    bf16x8 pa_l = *(const bf16x8*)(spl + (h*16 + fr)*40 + fko);
    #pragma unroll
    for (int ct = 0; ct < 6; ++ct) {
      const int col = h*DG_ + ct*16 + fr;
      const size_t vaddr = ((size_t)b*FEAT_ + col)*KPAD_ + fko;
      bf16x8 vh = *(const bf16x8*)(vwT_hi + vaddr);
      bf16x8 vl = *(const bf16x8*)(vwT_lo + vaddr);
      f32x4 o = {};
      o = __builtin_amdgcn_mfma_f32_16x16x32_bf16(pa_h, vh, o, 0, 0, 0);
      o = __builtin_amdgcn_mfma_f32_16x16x32_bf16(pa_h, vl, o, 0, 0, 0);
      o = __builtin_amdgcn_mfma_f32_16x16x32_bf16(pa_l, vh, o, 0, 0, 0);
      const float bv = bout[col];
      #pragma unroll
      for (int r = 0; r < 4; ++r)
        out[((size_t)b*N_ + row0 + fq*4 + r)*FEAT_ + col] = o[r] + bv;
    }
  }
}

extern "C" void kernel_launch(void* const* d_in, const int* in_sizes, int n_in,
                              void* d_out, int out_size, void* d_ws, size_t ws_size,
                              hipStream_t stream) {
  const float* roi  = (const float*)d_in[0];
  const int*   adj  = (const int*)  d_in[1];
  const float* pe   = (const float*)d_in[2];
  const float* lb   = (const float*)d_in[3];
  const float* aux  = (const float*)d_in[4];
  const float* Wq   = (const float*)d_in[5];
  const float* bq   = (const float*)d_in[6];
  const float* Wk   = (const float*)d_in[7];
  const float* bk   = (const float*)d_in[8];
  const float* Wpos = (const float*)d_in[9];
  const float* bpos = (const float*)d_in[10];
  const float* m_k  = (const float*)d_in[11];
  const float* m_v  = (const float*)d_in[12];
  const float* Wout = (const float*)d_in[13];
  const float* bout = (const float*)d_in[14];
  float* out = (float*)d_out;

  char* pw = (char*)d_ws;
  auto carve = [&](size_t bytes) -> void* {
    void* r = pw; pw += (bytes + 255) & ~(size_t)255; return r;
  };
  bf16*  Abf    = (bf16*) carve((size_t)ROWS_*FEAT_*2);
  bf16*  qbuf   = (bf16*) carve((size_t)ROWS_*FEAT_*2);
  bf16*  Wq_t   = (bf16*) carve((size_t)FEAT_*FEAT_*2);
  bf16*  Wk_t   = (bf16*) carve((size_t)FEAT_*FEAT_*2);
  bf16*  Whi    = (bf16*) carve((size_t)FEAT_*FEAT_*2);
  bf16*  Wlo    = (bf16*) carve((size_t)FEAT_*FEAT_*2);
  bf16*  Vbf    = (bf16*) carve((size_t)B_*KPAD_*FEAT_*2);
  bf16*  kbuf   = (bf16*) carve((size_t)B_*KPAD_*FEAT_*2);
  bf16*  vwT_hi = (bf16*) carve((size_t)B_*FEAT_*KPAD_*2);
  bf16*  vwT_lo = (bf16*) carve((size_t)B_*FEAT_*KPAD_*2);
  float* posb   = (float*)carve((size_t)ROWS_*160*4);

  prep_kernel<<<dim3(1024), dim3(256), 0, stream>>>(Wq, Wk, Wout, roi, aux, m_v, m_k,
                                                    Wq_t, Wk_t, Whi, Wlo, Vbf, kbuf);
  convert_roi_kernel<<<dim3(6144), dim3(256), 0, stream>>>(roi, Abf);
  posbias_kernel<<<dim3(16384), dim3(64), 0, stream>>>(pe, Wpos, bpos, posb);
  gemm128_kernel<<<dim3(6, 128), dim3(256), 0, stream>>>(Abf, Wq_t, bq, qbuf);
  gemm_small2_kernel<<<dim3(48, 64), dim3(64), 0, stream>>>(Abf, Wk_t, Vbf, Whi, Wlo,
                                                            bk, kbuf, vwT_hi, vwT_lo);
  attn_kernel<<<dim3(64, 16), dim3(256), 0, stream>>>(qbuf, kbuf, vwT_hi, vwT_lo,
                                                      posb, adj, lb, bout, out);
}

// Round 4
// 137.872 us; speedup vs baseline: 2.2926x; 1.0030x over previous
//
#include <hip/hip_runtime.h>
#include <hip/hip_bf16.h>
#include <cstdint>

typedef __bf16 bf16;
typedef __bf16 bf16x4 __attribute__((ext_vector_type(4)));
typedef __bf16 bf16x8 __attribute__((ext_vector_type(8)));
typedef float f32x4 __attribute__((ext_vector_type(4)));

#define B_ 16
#define N_ 1024
#define FEAT_ 768
#define H_ 8
#define NONGT_ 20
#define M_ 10
#define POS_ 64
#define DG_ 96
#define KTOT_ 30
#define KPAD_ 32
#define ROWS_ (B_*N_)
#define SCALE_M 9.797958971132712f
#define INV_SQRT_DG 0.10206207261596575f
#define NEG_ -9.0e15f

__device__ __forceinline__ void gload16(const void* g, void* lds) {
  __builtin_amdgcn_global_load_lds(
      (const __attribute__((address_space(1))) unsigned int*)g,
      (__attribute__((address_space(3))) unsigned int*)lds, 16, 0, 0);
}

__device__ __forceinline__ bf16x8 cvt8(float4 a, float4 b) {
  bf16x8 o;
  o[0]=(bf16)a.x; o[1]=(bf16)a.y; o[2]=(bf16)a.z; o[3]=(bf16)a.w;
  o[4]=(bf16)b.x; o[5]=(bf16)b.y; o[6]=(bf16)b.z; o[7]=(bf16)b.w;
  return o;
}

// ---------------- prep: weight transposes/conversions + V build + mk rows of kbuf ----
__global__ void prep_kernel(const float* __restrict__ Wq, const float* __restrict__ Wk,
                            const float* __restrict__ Wout, const float* __restrict__ roi,
                            const float* __restrict__ aux, const float* __restrict__ m_v,
                            const float* __restrict__ m_k,
                            bf16* __restrict__ Wq_t, bf16* __restrict__ Wk_t,
                            bf16* __restrict__ Whi, bf16* __restrict__ Wlo,
                            bf16* __restrict__ Vbf, bf16* __restrict__ kbuf)
{
  int idx = blockIdx.x * blockDim.x + threadIdx.x;
  int stride = gridDim.x * blockDim.x;
  for (int i = idx; i < FEAT_*FEAT_; i += stride) {
    int n = i / FEAT_, k = i % FEAT_;
    Wq_t[i] = (bf16)Wq[k*FEAT_ + n];
    Wk_t[i] = (bf16)Wk[k*FEAT_ + n];
    float w = Wout[i];              // Wout is [(h*DG+g)][f] row-major already
    bf16 hi = (bf16)w;
    Whi[i] = hi;
    Wlo[i] = (bf16)(w - (float)hi);
  }
  for (int i = idx; i < B_*KPAD_*FEAT_; i += stride) {
    int f = i % FEAT_;
    int r = (i / FEAT_) % KPAD_;
    int b = i / (FEAT_*KPAD_);
    float v;
    if (r < NONGT_)      v = roi[((size_t)b*N_ + r)*FEAT_ + f];
    else if (r < KTOT_)  v = SCALE_M * m_v[(r-NONGT_)*FEAT_ + f] * aux[b*FEAT_ + f];
    else                 v = 0.f;
    Vbf[i] = (bf16)v;
  }
  // kbuf rows 20..31 (mk keys + zero pad); rows 0..19 written by mid_kernel role B
  for (int i = idx; i < B_*12*FEAT_; i += stride) {
    int f = i % FEAT_;
    int rr = (i / FEAT_) % 12;
    int b = i / (FEAT_*12);
    float v = (rr < M_) ? SCALE_M * m_k[rr*FEAT_ + f] * aux[b*FEAT_ + f] : 0.f;
    kbuf[((size_t)b*KPAD_ + NONGT_ + rr)*FEAT_ + f] = (bf16)v;
  }
}

// ---------------- fused mid phase: Q-GEMM + small GEMMs + posbias, role by blockIdx ---
// grid 5632 = 256 stripes x 22; stripe layout {3 A, 3 B, 16 C} for CU co-residency.
__global__ __launch_bounds__(256, 4) void mid_kernel(
    const float* __restrict__ roi, const bf16* __restrict__ Wq_t,
    const float* __restrict__ bq, bf16* __restrict__ qbuf,
    const bf16* __restrict__ Wk_t, const bf16* __restrict__ Vbf,
    const bf16* __restrict__ Whi, const bf16* __restrict__ Wlo,
    const float* __restrict__ bk, bf16* __restrict__ kbuf,
    bf16* __restrict__ vwT_hi, bf16* __restrict__ vwT_lo,
    const float* __restrict__ pe, const float* __restrict__ Wpos,
    const float* __restrict__ bpos, float* __restrict__ posb)
{
  __shared__ __align__(16) char smem[24576];
  const int tid = threadIdx.x;
  const int w = tid >> 6, l = tid & 63;
  const int bx = blockIdx.x;
  const int r22 = bx % 22, s22 = bx / 22;

  if (r22 < 3) {
    // ================= role A: Q-GEMM 128x128 tile =================
    const int aidx = s22*3 + r22;            // [0,768)
    const int nbase = (aidx % 6) * 128;
    const int mbase = (aidx / 6) * 128;
    bf16* sA = (bf16*)smem;                  // [128][32]
    bf16* sB = (bf16*)(smem + 8192);         // [128][32]
    const int wr = w >> 1, wc = w & 1;
    const int srow = tid >> 2;
    const int scol = (tid & 3) << 3;
    const float* Ag0 = roi + (size_t)(mbase + srow)*FEAT_ + scol;
    const bf16*  Bg0 = Wq_t + (size_t)(nbase + srow)*FEAT_ + scol;
    const bf16*  Bg1 = Bg0 + (size_t)64*FEAT_;
    bf16* ldsB0 = sB + w*512;
    bf16* ldsB1 = sB + 2048 + w*512;
    const int fr = l & 15, fko = (l >> 4) << 3;
    f32x4 acc[4][4] = {};
    for (int kt = 0; kt < FEAT_/32; ++kt) {
      __syncthreads();
      gload16(Bg0 + kt*32, ldsB0);
      gload16(Bg1 + kt*32, ldsB1);
      const float* Ap = Ag0 + kt*32;
      float4 a0 = *(const float4*)Ap;
      float4 a1 = *(const float4*)(Ap + 4);
      float4 b0 = *(const float4*)(Ap + (size_t)64*FEAT_);
      float4 b1 = *(const float4*)(Ap + (size_t)64*FEAT_ + 4);
      *(bf16x8*)(sA + srow*32 + scol) = cvt8(a0, a1);
      *(bf16x8*)(sA + (64 + srow)*32 + scol) = cvt8(b0, b1);
      __syncthreads();
      bf16x8 af[4], bff[4];
      #pragma unroll
      for (int m = 0; m < 4; ++m)
        af[m] = *(const bf16x8*)(sA + (wr*64 + m*16 + fr)*32 + fko);
      #pragma unroll
      for (int n = 0; n < 4; ++n)
        bff[n] = *(const bf16x8*)(sB + (wc*64 + n*16 + fr)*32 + fko);
      #pragma unroll
      for (int m = 0; m < 4; ++m) {
        #pragma unroll
        for (int n = 0; n < 4; ++n)
          acc[m][n] = __builtin_amdgcn_mfma_f32_16x16x32_bf16(af[m], bff[n], acc[m][n], 0, 0, 0);
      }
    }
    const int fq = l >> 4;
    #pragma unroll
    for (int n = 0; n < 4; ++n) {
      const int col = nbase + wc*64 + n*16 + fr;
      const float bv = bq[col];
      #pragma unroll
      for (int m = 0; m < 4; ++m) {
        const int row = mbase + wr*64 + m*16 + fq*4;
        #pragma unroll
        for (int r = 0; r < 4; ++r)
          qbuf[(size_t)(row + r)*FEAT_ + col] = (bf16)(acc[m][n][r] + bv);
      }
    }
  } else if (r22 < 6) {
    // ================= role B: small GEMMs, one wave per 16x16 tile =================
    const int idx = (s22*3 + (r22 - 3))*4 + w;   // [0,3072)
    const int cbase = (idx % 48) * 16;
    const int by = idx / 48;                     // [0,64)
    const int fr = l & 15, fko = (l >> 4) << 3, fq = l >> 4;
    f32x4 acc = {};
    if (by < 32) {
      const float* Ap = roi + ((size_t)(by >> 1)*N_ + (by & 1)*16 + fr)*FEAT_ + fko;
      const bf16* Bp = Wk_t + (size_t)(cbase + fr)*FEAT_ + fko;
      #pragma unroll
      for (int kt = 0; kt < FEAT_/32; ++kt) {
        float4 a0 = *(const float4*)(Ap + kt*32);
        float4 a1 = *(const float4*)(Ap + kt*32 + 4);
        bf16x8 b = *(const bf16x8*)(Bp + kt*32);
        acc = __builtin_amdgcn_mfma_f32_16x16x32_bf16(cvt8(a0, a1), b, acc, 0, 0, 0);
      }
      const float bv = bk[cbase + fr];
      #pragma unroll
      for (int r = 0; r < 4; ++r) {
        const int rl = (by & 1)*16 + fq*4 + r;       // local key row 0..31
        if (rl < NONGT_)
          kbuf[((size_t)(by >> 1)*KPAD_ + rl)*FEAT_ + cbase + fr] = (bf16)(acc[r] + bv);
      }
    } else {
      const int rt = by - 32;
      const bf16* Ap = Vbf + ((size_t)rt*16 + fr)*FEAT_ + fko;
      const bf16* B1 = Whi + (size_t)(cbase + fr)*FEAT_ + fko;
      const bf16* B2 = Wlo + (size_t)(cbase + fr)*FEAT_ + fko;
      f32x4 acc2 = {};
      #pragma unroll
      for (int kt = 0; kt < FEAT_/32; ++kt) {
        bf16x8 a = *(const bf16x8*)(Ap + kt*32);
        acc  = __builtin_amdgcn_mfma_f32_16x16x32_bf16(a, *(const bf16x8*)(B1 + kt*32), acc,  0, 0, 0);
        acc2 = __builtin_amdgcn_mfma_f32_16x16x32_bf16(a, *(const bf16x8*)(B2 + kt*32), acc2, 0, 0, 0);
      }
      #pragma unroll
      for (int r = 0; r < 4; ++r) {
        const int grow = rt*16 + fq*4 + r;           // 0..511
        const int b = grow >> 5, key = grow & 31;
        float vv = acc[r] + acc2[r];
        bf16 vh = (bf16)vv;
        size_t addr = ((size_t)b*FEAT_ + cbase + fr)*KPAD_ + key;
        vwT_hi[addr] = vh;
        vwT_lo[addr] = (bf16)(vv - (float)vh);
      }
    }
  } else {
    // ================= role C: posbias, one wave per row, 4 rows/block =================
    const int cidx = s22*16 + (r22 - 6);         // [0,4096)
    const int row = cidx*4 + w;                  // [0,16384)
    float* spe  = (float*)smem + w*1360;         // [20][68] per wave
    float* swpT = (float*)(smem + 21760);        // [8][68]
    float* sbp  = (float*)(smem + 21760 + 2176);
    const float* per = pe + (size_t)row*NONGT_*POS_;
    for (int i = l; i < NONGT_*POS_; i += 64) spe[(i >> 6)*68 + (i & 63)] = per[i];
    for (int i = tid; i < POS_*H_; i += 256) swpT[(i & 7)*68 + (i >> 3)] = Wpos[i];
    if (tid < H_) sbp[tid] = bpos[tid];
    __syncthreads();
    #pragma unroll
    for (int t = 0; t < 3; ++t) {
      int idx = t*64 + l;
      if (idx < NONGT_*H_) {
        int j = idx >> 3, h = idx & 7;
        float s = sbp[h];
        const float4* a4 = (const float4*)(spe + j*68);
        const float4* b4 = (const float4*)(swpT + h*68);
        #pragma unroll
        for (int p4 = 0; p4 < 16; ++p4) {
          float4 a = a4[p4], bv = b4[p4];
          s += a.x*bv.x + a.y*bv.y + a.z*bv.z + a.w*bv.w;
        }
        s = fmaxf(s, 0.f);
        posb[(size_t)row*160 + h*20 + j] = __logf(fmaxf(s, 1e-6f));
      }
    }
  }
}

// ---------------- fused attention: QK^T (MFMA) + softmax + PV (MFMA) ----------------
// grid (ntile=64, b=16), 256 threads = 4 waves; wave w owns heads 2w, 2w+1.
__global__ __launch_bounds__(256, 4) void attn_kernel(
    const bf16* __restrict__ qbuf, const bf16* __restrict__ kbuf,
    const bf16* __restrict__ vwT_hi, const bf16* __restrict__ vwT_lo,
    const float* __restrict__ posb, const int* __restrict__ adj,
    const float* __restrict__ lb, const float* __restrict__ bout,
    float* __restrict__ out)
{
  __shared__ __align__(16) bf16 sph[H_*16*40];   // p hi, padded key stride 40
  __shared__ __align__(16) bf16 spl[H_*16*40];   // p lo
  const int tid = threadIdx.x;
  const int w = tid >> 6, l = tid & 63;
  const int fr = l & 15, fq = l >> 4, fko = fq << 3;
  const int row0 = blockIdx.x * 16;
  const int b = blockIdx.y;
  const size_t rabs = (size_t)b*N_ + row0 + fr;   // this lane's q-row (for q/posb/adj/lb)

  #pragma unroll
  for (int hi2 = 0; hi2 < 2; ++hi2) {
    const int h = w*2 + hi2;
    // ---- QK^T: C[key][qrow], 2 key-tiles, K=96 ----
    const bf16* kp = kbuf + (size_t)b*KPAD_*FEAT_ + h*DG_ + fko;
    const bf16* qp = qbuf + rabs*FEAT_ + h*DG_ + fko;
    f32x4 acc0 = {}, acc1 = {};
    #pragma unroll
    for (int kt = 0; kt < 3; ++kt) {
      bf16x8 qa = *(const bf16x8*)(qp + kt*32);
      bf16x8 k0 = *(const bf16x8*)(kp + (size_t)fr*FEAT_ + kt*32);
      bf16x8 k1 = *(const bf16x8*)(kp + (size_t)(16 + fr)*FEAT_ + kt*32);
      acc0 = __builtin_amdgcn_mfma_f32_16x16x32_bf16(k0, qa, acc0, 0, 0, 0);
      acc1 = __builtin_amdgcn_mfma_f32_16x16x32_bf16(k1, qa, acc1, 0, 0, 0);
    }
    // ---- bias + mask; lane holds keys {fq*4+r, 16+fq*4+r} of q-row (row0+fr) ----
    const float* pbr = posb + rabs*160 + h*20;
    const int*   adjr = adj + rabs*20;
    const float* lbr  = lb  + rabs*20;
    float lg[2][4];
    #pragma unroll
    for (int r = 0; r < 4; ++r) {
      int j0 = fq*4 + r;
      float v0 = acc0[r] * INV_SQRT_DG;
      v0 = (adjr[j0] > 0 ? v0 + pbr[j0] : NEG_) + lbr[j0];
      lg[0][r] = v0;
      int j1 = 16 + fq*4 + r;
      float v1 = acc1[r] * INV_SQRT_DG;
      if (j1 < NONGT_)      v1 = (adjr[j1] > 0 ? v1 + pbr[j1] : NEG_) + lbr[j1];
      else if (j1 >= KTOT_) v1 = -3.0e38f;
      lg[1][r] = v1;
    }
    // ---- softmax over 32 keys: 8 regs x 4 lanes (fq) ----
    float m = lg[0][0];
    #pragma unroll
    for (int jt = 0; jt < 2; ++jt)
      #pragma unroll
      for (int r = 0; r < 4; ++r) m = fmaxf(m, lg[jt][r]);
    m = fmaxf(m, __shfl_xor(m, 16));
    m = fmaxf(m, __shfl_xor(m, 32));
    float s = 0.f;
    float e[2][4];
    #pragma unroll
    for (int jt = 0; jt < 2; ++jt)
      #pragma unroll
      for (int r = 0; r < 4; ++r) { e[jt][r] = __expf(lg[jt][r] - m); s += e[jt][r]; }
    s += __shfl_xor(s, 16);
    s += __shfl_xor(s, 32);
    const float inv = 1.f / s;
    // ---- p -> hi/lo bf16 -> LDS (wave-private region, no barrier) ----
    #pragma unroll
    for (int jt = 0; jt < 2; ++jt) {
      bf16x4 ph, pl;
      #pragma unroll
      for (int r = 0; r < 4; ++r) {
        float p = e[jt][r] * inv;
        ph[r] = (bf16)p;
        pl[r] = (bf16)(p - (float)ph[r]);
      }
      const int off = (h*16 + fr)*40 + jt*16 + fq*4;
      *(bf16x4*)(sph + off) = ph;
      *(bf16x4*)(spl + off) = pl;
    }
    // ---- PV: out[16 rows x 96 cols] via 6 col-tiles, K=32 (1 k-step), 3 passes ----
    bf16x8 pa_h = *(const bf16x8*)(sph + (h*16 + fr)*40 + fko);
    bf16x8 pa_l = *(const bf16x8*)(spl + (h*16 + fr)*40 + fko);
    #pragma unroll
    for (int ct = 0; ct < 6; ++ct) {
      const int col = h*DG_ + ct*16 + fr;
      const size_t vaddr = ((size_t)b*FEAT_ + col)*KPAD_ + fko;
      bf16x8 vh = *(const bf16x8*)(vwT_hi + vaddr);
      bf16x8 vl = *(const bf16x8*)(vwT_lo + vaddr);
      f32x4 o = {};
      o = __builtin_amdgcn_mfma_f32_16x16x32_bf16(pa_h, vh, o, 0, 0, 0);
      o = __builtin_amdgcn_mfma_f32_16x16x32_bf16(pa_h, vl, o, 0, 0, 0);
      o = __builtin_amdgcn_mfma_f32_16x16x32_bf16(pa_l, vh, o, 0, 0, 0);
      const float bv = bout[col];
      #pragma unroll
      for (int r = 0; r < 4; ++r)
        out[((size_t)b*N_ + row0 + fq*4 + r)*FEAT_ + col] = o[r] + bv;
    }
  }
}

extern "C" void kernel_launch(void* const* d_in, const int* in_sizes, int n_in,
                              void* d_out, int out_size, void* d_ws, size_t ws_size,
                              hipStream_t stream) {
  const float* roi  = (const float*)d_in[0];
  const int*   adj  = (const int*)  d_in[1];
  const float* pe   = (const float*)d_in[2];
  const float* lb   = (const float*)d_in[3];
  const float* aux  = (const float*)d_in[4];
  const float* Wq   = (const float*)d_in[5];
  const float* bq   = (const float*)d_in[6];
  const float* Wk   = (const float*)d_in[7];
  const float* bk   = (const float*)d_in[8];
  const float* Wpos = (const float*)d_in[9];
  const float* bpos = (const float*)d_in[10];
  const float* m_k  = (const float*)d_in[11];
  const float* m_v  = (const float*)d_in[12];
  const float* Wout = (const float*)d_in[13];
  const float* bout = (const float*)d_in[14];
  float* out = (float*)d_out;

  char* pw = (char*)d_ws;
  auto carve = [&](size_t bytes) -> void* {
    void* r = pw; pw += (bytes + 255) & ~(size_t)255; return r;
  };
  bf16*  qbuf   = (bf16*) carve((size_t)ROWS_*FEAT_*2);
  bf16*  Wq_t   = (bf16*) carve((size_t)FEAT_*FEAT_*2);
  bf16*  Wk_t   = (bf16*) carve((size_t)FEAT_*FEAT_*2);
  bf16*  Whi    = (bf16*) carve((size_t)FEAT_*FEAT_*2);
  bf16*  Wlo    = (bf16*) carve((size_t)FEAT_*FEAT_*2);
  bf16*  Vbf    = (bf16*) carve((size_t)B_*KPAD_*FEAT_*2);
  bf16*  kbuf   = (bf16*) carve((size_t)B_*KPAD_*FEAT_*2);
  bf16*  vwT_hi = (bf16*) carve((size_t)B_*FEAT_*KPAD_*2);
  bf16*  vwT_lo = (bf16*) carve((size_t)B_*FEAT_*KPAD_*2);
  float* posb   = (float*)carve((size_t)ROWS_*160*4);

  prep_kernel<<<dim3(1024), dim3(256), 0, stream>>>(Wq, Wk, Wout, roi, aux, m_v, m_k,
                                                    Wq_t, Wk_t, Whi, Wlo, Vbf, kbuf);
  mid_kernel<<<dim3(5632), dim3(256), 0, stream>>>(roi, Wq_t, bq, qbuf,
                                                   Wk_t, Vbf, Whi, Wlo, bk, kbuf,
                                                   vwT_hi, vwT_lo,
                                                   pe, Wpos, bpos, posb);
  attn_kernel<<<dim3(64, 16), dim3(256), 0, stream>>>(qbuf, kbuf, vwT_hi, vwT_lo,
                                                      posb, adj, lb, bout, out);
}

// Round 5
// 133.121 us; speedup vs baseline: 2.3744x; 1.0357x over previous
//
#include <hip/hip_runtime.h>
#include <hip/hip_bf16.h>
#include <cstdint>

typedef __bf16 bf16;
typedef __bf16 bf16x4 __attribute__((ext_vector_type(4)));
typedef __bf16 bf16x8 __attribute__((ext_vector_type(8)));
typedef float f32x4 __attribute__((ext_vector_type(4)));

#define B_ 16
#define N_ 1024
#define FEAT_ 768
#define H_ 8
#define NONGT_ 20
#define M_ 10
#define POS_ 64
#define DG_ 96
#define KTOT_ 30
#define KPAD_ 32
#define ROWS_ (B_*N_)
#define SCALE_M 9.797958971132712f
#define INV_SQRT_DG 0.10206207261596575f
#define NEG_ -9.0e15f

__device__ __forceinline__ void gload16(const void* g, void* lds) {
  __builtin_amdgcn_global_load_lds(
      (const __attribute__((address_space(1))) unsigned int*)g,
      (__attribute__((address_space(3))) unsigned int*)lds, 16, 0, 0);
}

__device__ __forceinline__ bf16x8 cvt8(float4 a, float4 b) {
  bf16x8 o;
  o[0]=(bf16)a.x; o[1]=(bf16)a.y; o[2]=(bf16)a.z; o[3]=(bf16)a.w;
  o[4]=(bf16)b.x; o[5]=(bf16)b.y; o[6]=(bf16)b.z; o[7]=(bf16)b.w;
  return o;
}

// ---------------- prep: weights + V + mk-keys + roi->bf16 (merged convert) ----------
__global__ void prep_kernel(const float* __restrict__ Wq, const float* __restrict__ Wk,
                            const float* __restrict__ Wout, const float* __restrict__ roi,
                            const float* __restrict__ aux, const float* __restrict__ m_v,
                            const float* __restrict__ m_k,
                            bf16* __restrict__ Wq_t, bf16* __restrict__ Wk_t,
                            bf16* __restrict__ Whi, bf16* __restrict__ Wlo,
                            bf16* __restrict__ Vbf, bf16* __restrict__ kbuf,
                            bf16* __restrict__ Abf)
{
  int idx = blockIdx.x * blockDim.x + threadIdx.x;
  int stride = gridDim.x * blockDim.x;
  for (int i = idx; i < FEAT_*FEAT_; i += stride) {
    int n = i / FEAT_, k = i % FEAT_;
    Wq_t[i] = (bf16)Wq[k*FEAT_ + n];
    Wk_t[i] = (bf16)Wk[k*FEAT_ + n];
    float w = Wout[i];              // Wout is [(h*DG+g)][f] row-major already
    bf16 hi = (bf16)w;
    Whi[i] = hi;
    Wlo[i] = (bf16)(w - (float)hi);
  }
  for (int i = idx; i < B_*KPAD_*FEAT_; i += stride) {
    int f = i % FEAT_;
    int r = (i / FEAT_) % KPAD_;
    int b = i / (FEAT_*KPAD_);
    float v;
    if (r < NONGT_)      v = roi[((size_t)b*N_ + r)*FEAT_ + f];
    else if (r < KTOT_)  v = SCALE_M * m_v[(r-NONGT_)*FEAT_ + f] * aux[b*FEAT_ + f];
    else                 v = 0.f;
    Vbf[i] = (bf16)v;
  }
  // kbuf rows 20..31 (mk keys + zero pad); rows 0..19 written by gemm_fused small role
  for (int i = idx; i < B_*12*FEAT_; i += stride) {
    int f = i % FEAT_;
    int rr = (i / FEAT_) % 12;
    int b = i / (FEAT_*12);
    float v = (rr < M_) ? SCALE_M * m_k[rr*FEAT_ + f] * aux[b*FEAT_ + f] : 0.f;
    kbuf[((size_t)b*KPAD_ + NONGT_ + rr)*FEAT_ + f] = (bf16)v;
  }
  // roi -> bf16 (vectorized)
  const int total8 = ROWS_*FEAT_/8;
  for (int i = idx; i < total8; i += stride) {
    const float4* p = (const float4*)(roi + (size_t)i*8);
    *(bf16x8*)(Abf + (size_t)i*8) = cvt8(p[0], p[1]);
  }
}

// ---------------- fused GEMM phase ----------------
// bx < 768 : Q-GEMM 128x128 tile, XCD-grouped so the 6 col-tiles of one A-slab run
//            on one XCD (A-slab + Wq_t stay L2-resident -> re-reads are L2 hits).
// bx >= 768: small GEMMs, one wave per 16x16 tile (K-GEMM + VW-GEMM).
__global__ __launch_bounds__(256, 2) void gemm_fused_kernel(
    const bf16* __restrict__ A, const bf16* __restrict__ Wq_t,
    const float* __restrict__ bq, bf16* __restrict__ qbuf,
    const bf16* __restrict__ Wk_t, const bf16* __restrict__ Vbf,
    const bf16* __restrict__ Whi, const bf16* __restrict__ Wlo,
    const float* __restrict__ bk, bf16* __restrict__ kbuf,
    bf16* __restrict__ vwT_hi, bf16* __restrict__ vwT_lo)
{
  __shared__ __align__(16) bf16 sA[128*32];
  __shared__ __align__(16) bf16 sB[128*32];
  const int tid = threadIdx.x;
  const int w = tid >> 6, l = tid & 63;
  const int bx = blockIdx.x;
  const int fr = l & 15, fq = l >> 4, fko = fq << 3;

  if (bx < 768) {
    // ---- XCD-grouped mapping: XCD x owns mtiles {x, x+8, ...}, ctiles consecutive ----
    const int x = bx & 7, j = bx >> 3;
    const int mbase = (x + 8*(j/6)) * 128;
    const int nbase = (j % 6) * 128;
    const int wr = w >> 1, wc = w & 1;
    const int srow = tid >> 2;
    const int scol = (tid & 3) << 3;
    const bf16* Ag0 = A + (size_t)(mbase + srow)*FEAT_ + scol;
    const bf16* Ag1 = Ag0 + (size_t)64*FEAT_;
    const bf16* Bg0 = Wq_t + (size_t)(nbase + srow)*FEAT_ + scol;
    const bf16* Bg1 = Bg0 + (size_t)64*FEAT_;
    bf16* ldsA0 = sA + w*512;
    bf16* ldsA1 = sA + 2048 + w*512;
    bf16* ldsB0 = sB + w*512;
    bf16* ldsB1 = sB + 2048 + w*512;
    f32x4 acc[4][4] = {};
    for (int kt = 0; kt < FEAT_/32; ++kt) {
      __syncthreads();
      gload16(Ag0 + kt*32, ldsA0);
      gload16(Ag1 + kt*32, ldsA1);
      gload16(Bg0 + kt*32, ldsB0);
      gload16(Bg1 + kt*32, ldsB1);
      __syncthreads();
      bf16x8 af[4], bff[4];
      #pragma unroll
      for (int m = 0; m < 4; ++m)
        af[m] = *(const bf16x8*)(sA + (wr*64 + m*16 + fr)*32 + fko);
      #pragma unroll
      for (int n = 0; n < 4; ++n)
        bff[n] = *(const bf16x8*)(sB + (wc*64 + n*16 + fr)*32 + fko);
      #pragma unroll
      for (int m = 0; m < 4; ++m) {
        #pragma unroll
        for (int n = 0; n < 4; ++n)
          acc[m][n] = __builtin_amdgcn_mfma_f32_16x16x32_bf16(af[m], bff[n], acc[m][n], 0, 0, 0);
      }
    }
    #pragma unroll
    for (int n = 0; n < 4; ++n) {
      const int col = nbase + wc*64 + n*16 + fr;
      const float bv = bq[col];
      #pragma unroll
      for (int m = 0; m < 4; ++m) {
        const int row = mbase + wr*64 + m*16 + fq*4;
        #pragma unroll
        for (int r = 0; r < 4; ++r)
          qbuf[(size_t)(row + r)*FEAT_ + col] = (bf16)(acc[m][n][r] + bv);
      }
    }
  } else {
    // ---- small GEMMs: wave-task widx in [0, 3072) ----
    const int widx = (bx - 768)*4 + w;
    const int cbase = (widx % 48) * 16;
    const int by = widx / 48;                 // [0,64)
    f32x4 acc = {};
    if (by < 32) {
      const bf16* Ap = A + ((size_t)(by >> 1)*N_ + (by & 1)*16 + fr)*FEAT_ + fko;
      const bf16* Bp = Wk_t + (size_t)(cbase + fr)*FEAT_ + fko;
      #pragma unroll
      for (int kt = 0; kt < FEAT_/32; ++kt) {
        bf16x8 a = *(const bf16x8*)(Ap + kt*32);
        bf16x8 b = *(const bf16x8*)(Bp + kt*32);
        acc = __builtin_amdgcn_mfma_f32_16x16x32_bf16(a, b, acc, 0, 0, 0);
      }
      const float bv = bk[cbase + fr];
      #pragma unroll
      for (int r = 0; r < 4; ++r) {
        const int rl = (by & 1)*16 + fq*4 + r;       // local key row 0..31
        if (rl < NONGT_)
          kbuf[((size_t)(by >> 1)*KPAD_ + rl)*FEAT_ + cbase + fr] = (bf16)(acc[r] + bv);
      }
    } else {
      const int rt = by - 32;
      const bf16* Ap = Vbf + ((size_t)rt*16 + fr)*FEAT_ + fko;
      const bf16* B1 = Whi + (size_t)(cbase + fr)*FEAT_ + fko;
      const bf16* B2 = Wlo + (size_t)(cbase + fr)*FEAT_ + fko;
      f32x4 acc2 = {};
      #pragma unroll
      for (int kt = 0; kt < FEAT_/32; ++kt) {
        bf16x8 a = *(const bf16x8*)(Ap + kt*32);
        acc  = __builtin_amdgcn_mfma_f32_16x16x32_bf16(a, *(const bf16x8*)(B1 + kt*32), acc,  0, 0, 0);
        acc2 = __builtin_amdgcn_mfma_f32_16x16x32_bf16(a, *(const bf16x8*)(B2 + kt*32), acc2, 0, 0, 0);
      }
      #pragma unroll
      for (int r = 0; r < 4; ++r) {
        const int grow = rt*16 + fq*4 + r;           // 0..511
        const int b = grow >> 5, key = grow & 31;
        float vv = acc[r] + acc2[r];
        bf16 vh = (bf16)vv;
        size_t addr = ((size_t)b*FEAT_ + cbase + fr)*KPAD_ + key;
        vwT_hi[addr] = vh;
        vwT_lo[addr] = (bf16)(vv - (float)vh);
      }
    }
  }
}

// ---------------- position bias: log(max(relu(pe@Wpos+bpos),1e-6)) ----------------
__global__ __launch_bounds__(64, 4) void posbias_kernel(
    const float* __restrict__ pe, const float* __restrict__ Wpos,
    const float* __restrict__ bpos, float* __restrict__ posb)
{
  __shared__ __align__(16) float spe[NONGT_*68];
  __shared__ __align__(16) float swpT[H_*68];
  __shared__ float sbp[H_];
  const int row = blockIdx.x;
  const int l = threadIdx.x;
  const float* per = pe + (size_t)row*NONGT_*POS_;
  for (int i = l; i < NONGT_*POS_; i += 64) spe[(i >> 6)*68 + (i & 63)] = per[i];
  for (int i = l; i < POS_*H_; i += 64) swpT[(i & 7)*68 + (i >> 3)] = Wpos[i];
  if (l < H_) sbp[l] = bpos[l];
  __syncthreads();
  #pragma unroll
  for (int t = 0; t < 3; ++t) {
    int idx = t*64 + l;
    if (idx < NONGT_*H_) {
      int j = idx >> 3, h = idx & 7;
      float s = sbp[h];
      const float4* a4 = (const float4*)(spe + j*68);
      const float4* b4 = (const float4*)(swpT + h*68);
      #pragma unroll
      for (int p4 = 0; p4 < 16; ++p4) {
        float4 a = a4[p4], bv = b4[p4];
        s += a.x*bv.x + a.y*bv.y + a.z*bv.z + a.w*bv.w;
      }
      s = fmaxf(s, 0.f);
      posb[(size_t)row*160 + h*20 + j] = __logf(fmaxf(s, 1e-6f));
    }
  }
}

// ---------------- fused attention: QK^T (MFMA) + softmax + PV (MFMA) ----------------
// grid (ntile=64, b=16), 256 threads = 4 waves; wave w owns heads 2w, 2w+1.
__global__ __launch_bounds__(256, 4) void attn_kernel(
    const bf16* __restrict__ qbuf, const bf16* __restrict__ kbuf,
    const bf16* __restrict__ vwT_hi, const bf16* __restrict__ vwT_lo,
    const float* __restrict__ posb, const int* __restrict__ adj,
    const float* __restrict__ lb, const float* __restrict__ bout,
    float* __restrict__ out)
{
  __shared__ __align__(16) bf16 sph[H_*16*40];   // p hi, padded key stride 40
  __shared__ __align__(16) bf16 spl[H_*16*40];   // p lo
  const int tid = threadIdx.x;
  const int w = tid >> 6, l = tid & 63;
  const int fr = l & 15, fq = l >> 4, fko = fq << 3;
  const int row0 = blockIdx.x * 16;
  const int b = blockIdx.y;
  const size_t rabs = (size_t)b*N_ + row0 + fr;   // this lane's q-row (for q/posb/adj/lb)

  #pragma unroll
  for (int hi2 = 0; hi2 < 2; ++hi2) {
    const int h = w*2 + hi2;
    // ---- QK^T: C[key][qrow], 2 key-tiles, K=96 ----
    const bf16* kp = kbuf + (size_t)b*KPAD_*FEAT_ + h*DG_ + fko;
    const bf16* qp = qbuf + rabs*FEAT_ + h*DG_ + fko;
    f32x4 acc0 = {}, acc1 = {};
    #pragma unroll
    for (int kt = 0; kt < 3; ++kt) {
      bf16x8 qa = *(const bf16x8*)(qp + kt*32);
      bf16x8 k0 = *(const bf16x8*)(kp + (size_t)fr*FEAT_ + kt*32);
      bf16x8 k1 = *(const bf16x8*)(kp + (size_t)(16 + fr)*FEAT_ + kt*32);
      acc0 = __builtin_amdgcn_mfma_f32_16x16x32_bf16(k0, qa, acc0, 0, 0, 0);
      acc1 = __builtin_amdgcn_mfma_f32_16x16x32_bf16(k1, qa, acc1, 0, 0, 0);
    }
    // ---- bias + mask; lane holds keys {fq*4+r, 16+fq*4+r} of q-row (row0+fr) ----
    const float* pbr = posb + rabs*160 + h*20;
    const int*   adjr = adj + rabs*20;
    const float* lbr  = lb  + rabs*20;
    float lg[2][4];
    #pragma unroll
    for (int r = 0; r < 4; ++r) {
      int j0 = fq*4 + r;
      float v0 = acc0[r] * INV_SQRT_DG;
      v0 = (adjr[j0] > 0 ? v0 + pbr[j0] : NEG_) + lbr[j0];
      lg[0][r] = v0;
      int j1 = 16 + fq*4 + r;
      float v1 = acc1[r] * INV_SQRT_DG;
      if (j1 < NONGT_)      v1 = (adjr[j1] > 0 ? v1 + pbr[j1] : NEG_) + lbr[j1];
      else if (j1 >= KTOT_) v1 = -3.0e38f;
      lg[1][r] = v1;
    }
    // ---- softmax over 32 keys: 8 regs x 4 lanes (fq) ----
    float m = lg[0][0];
    #pragma unroll
    for (int jt = 0; jt < 2; ++jt)
      #pragma unroll
      for (int r = 0; r < 4; ++r) m = fmaxf(m, lg[jt][r]);
    m = fmaxf(m, __shfl_xor(m, 16));
    m = fmaxf(m, __shfl_xor(m, 32));
    float s = 0.f;
    float e[2][4];
    #pragma unroll
    for (int jt = 0; jt < 2; ++jt)
      #pragma unroll
      for (int r = 0; r < 4; ++r) { e[jt][r] = __expf(lg[jt][r] - m); s += e[jt][r]; }
    s += __shfl_xor(s, 16);
    s += __shfl_xor(s, 32);
    const float inv = 1.f / s;
    // ---- p -> hi/lo bf16 -> LDS (wave-private region, no barrier) ----
    #pragma unroll
    for (int jt = 0; jt < 2; ++jt) {
      bf16x4 ph, pl;
      #pragma unroll
      for (int r = 0; r < 4; ++r) {
        float p = e[jt][r] * inv;
        ph[r] = (bf16)p;
        pl[r] = (bf16)(p - (float)ph[r]);
      }
      const int off = (h*16 + fr)*40 + jt*16 + fq*4;
      *(bf16x4*)(sph + off) = ph;
      *(bf16x4*)(spl + off) = pl;
    }
    // ---- PV: out[16 rows x 96 cols] via 6 col-tiles, K=32 (1 k-step), 3 passes ----
    bf16x8 pa_h = *(const bf16x8*)(sph + (h*16 + fr)*40 + fko);
    bf16x8 pa_l = *(const bf16x8*)(spl + (h*16 + fr)*40 + fko);
    #pragma unroll
    for (int ct = 0; ct < 6; ++ct) {
      const int col = h*DG_ + ct*16 + fr;
      const size_t vaddr = ((size_t)b*FEAT_ + col)*KPAD_ + fko;
      bf16x8 vh = *(const bf16x8*)(vwT_hi + vaddr);
      bf16x8 vl = *(const bf16x8*)(vwT_lo + vaddr);
      f32x4 o = {};
      o = __builtin_amdgcn_mfma_f32_16x16x32_bf16(pa_h, vh, o, 0, 0, 0);
      o = __builtin_amdgcn_mfma_f32_16x16x32_bf16(pa_h, vl, o, 0, 0, 0);
      o = __builtin_amdgcn_mfma_f32_16x16x32_bf16(pa_l, vh, o, 0, 0, 0);
      const float bv = bout[col];
      #pragma unroll
      for (int r = 0; r < 4; ++r)
        out[((size_t)b*N_ + row0 + fq*4 + r)*FEAT_ + col] = o[r] + bv;
    }
  }
}

extern "C" void kernel_launch(void* const* d_in, const int* in_sizes, int n_in,
                              void* d_out, int out_size, void* d_ws, size_t ws_size,
                              hipStream_t stream) {
  const float* roi  = (const float*)d_in[0];
  const int*   adj  = (const int*)  d_in[1];
  const float* pe   = (const float*)d_in[2];
  const float* lb   = (const float*)d_in[3];
  const float* aux  = (const float*)d_in[4];
  const float* Wq   = (const float*)d_in[5];
  const float* bq   = (const float*)d_in[6];
  const float* Wk   = (const float*)d_in[7];
  const float* bk   = (const float*)d_in[8];
  const float* Wpos = (const float*)d_in[9];
  const float* bpos = (const float*)d_in[10];
  const float* m_k  = (const float*)d_in[11];
  const float* m_v  = (const float*)d_in[12];
  const float* Wout = (const float*)d_in[13];
  const float* bout = (const float*)d_in[14];
  float* out = (float*)d_out;

  char* pw = (char*)d_ws;
  auto carve = [&](size_t bytes) -> void* {
    void* r = pw; pw += (bytes + 255) & ~(size_t)255; return r;
  };
  bf16*  Abf    = (bf16*) carve((size_t)ROWS_*FEAT_*2);
  bf16*  qbuf   = (bf16*) carve((size_t)ROWS_*FEAT_*2);
  bf16*  Wq_t   = (bf16*) carve((size_t)FEAT_*FEAT_*2);
  bf16*  Wk_t   = (bf16*) carve((size_t)FEAT_*FEAT_*2);
  bf16*  Whi    = (bf16*) carve((size_t)FEAT_*FEAT_*2);
  bf16*  Wlo    = (bf16*) carve((size_t)FEAT_*FEAT_*2);
  bf16*  Vbf    = (bf16*) carve((size_t)B_*KPAD_*FEAT_*2);
  bf16*  kbuf   = (bf16*) carve((size_t)B_*KPAD_*FEAT_*2);
  bf16*  vwT_hi = (bf16*) carve((size_t)B_*FEAT_*KPAD_*2);
  bf16*  vwT_lo = (bf16*) carve((size_t)B_*FEAT_*KPAD_*2);
  float* posb   = (float*)carve((size_t)ROWS_*160*4);

  posbias_kernel<<<dim3(16384), dim3(64), 0, stream>>>(pe, Wpos, bpos, posb);
  prep_kernel<<<dim3(2048), dim3(256), 0, stream>>>(Wq, Wk, Wout, roi, aux, m_v, m_k,
                                                    Wq_t, Wk_t, Whi, Wlo, Vbf, kbuf, Abf);
  gemm_fused_kernel<<<dim3(1536), dim3(256), 0, stream>>>(Abf, Wq_t, bq, qbuf,
                                                          Wk_t, Vbf, Whi, Wlo, bk, kbuf,
                                                          vwT_hi, vwT_lo);
  attn_kernel<<<dim3(64, 16), dim3(256), 0, stream>>>(qbuf, kbuf, vwT_hi, vwT_lo,
                                                      posb, adj, lb, bout, out);
}

// Round 6
// 127.572 us; speedup vs baseline: 2.4777x; 1.0435x over previous
//
#include <hip/hip_runtime.h>
#include <hip/hip_bf16.h>
#include <cstdint>

typedef __bf16 bf16;
typedef __bf16 bf16x4 __attribute__((ext_vector_type(4)));
typedef __bf16 bf16x8 __attribute__((ext_vector_type(8)));
typedef float f32x4 __attribute__((ext_vector_type(4)));

#define B_ 16
#define N_ 1024
#define FEAT_ 768
#define H_ 8
#define NONGT_ 20
#define M_ 10
#define POS_ 64
#define DG_ 96
#define KTOT_ 30
#define KPAD_ 32
#define ROWS_ (B_*N_)
#define SCALE_M 9.797958971132712f
#define INV_SQRT_DG 0.10206207261596575f
#define NEG_ -9.0e15f

__device__ __forceinline__ void gload16(const void* g, void* lds) {
  __builtin_amdgcn_global_load_lds(
      (const __attribute__((address_space(1))) unsigned int*)g,
      (__attribute__((address_space(3))) unsigned int*)lds, 16, 0, 0);
}

__device__ __forceinline__ bf16x8 cvt8(float4 a, float4 b) {
  bf16x8 o;
  o[0]=(bf16)a.x; o[1]=(bf16)a.y; o[2]=(bf16)a.z; o[3]=(bf16)a.w;
  o[4]=(bf16)b.x; o[5]=(bf16)b.y; o[6]=(bf16)b.z; o[7]=(bf16)b.w;
  return o;
}

// ---------------- prep: weights + V + mk-keys (no more roi bulk convert) ----------
__global__ void prep_kernel(const float* __restrict__ Wq, const float* __restrict__ Wk,
                            const float* __restrict__ Wout, const float* __restrict__ roi,
                            const float* __restrict__ aux, const float* __restrict__ m_v,
                            const float* __restrict__ m_k,
                            bf16* __restrict__ Wq_t, bf16* __restrict__ Wk_t,
                            bf16* __restrict__ Whi, bf16* __restrict__ Wlo,
                            bf16* __restrict__ Vbf, bf16* __restrict__ kbuf)
{
  int idx = blockIdx.x * blockDim.x + threadIdx.x;
  int stride = gridDim.x * blockDim.x;
  // Wq/Wk transpose: coalesced READS, scattered writes (stores don't stall)
  for (int i = idx; i < FEAT_*FEAT_; i += stride) {
    int k = i / FEAT_, n = i % FEAT_;           // i walks Wq row-major
    bf16 q = (bf16)Wq[i], kk = (bf16)Wk[i];
    Wq_t[(size_t)n*FEAT_ + k] = q;
    Wk_t[(size_t)n*FEAT_ + k] = kk;
    float w = Wout[i];                           // Wout rows already [(h*DG+g)][f]
    bf16 hi = (bf16)w;
    Whi[i] = hi;
    Wlo[i] = (bf16)(w - (float)hi);
  }
  for (int i = idx; i < B_*KPAD_*FEAT_; i += stride) {
    int f = i % FEAT_;
    int r = (i / FEAT_) % KPAD_;
    int b = i / (FEAT_*KPAD_);
    float v;
    if (r < NONGT_)      v = roi[((size_t)b*N_ + r)*FEAT_ + f];
    else if (r < KTOT_)  v = SCALE_M * m_v[(r-NONGT_)*FEAT_ + f] * aux[b*FEAT_ + f];
    else                 v = 0.f;
    Vbf[i] = (bf16)v;
  }
  // kbuf rows 20..31 (mk keys + zero pad); rows 0..19 written by gemm_fused small role
  for (int i = idx; i < B_*12*FEAT_; i += stride) {
    int f = i % FEAT_;
    int rr = (i / FEAT_) % 12;
    int b = i / (FEAT_*12);
    float v = (rr < M_) ? SCALE_M * m_k[rr*FEAT_ + f] * aux[b*FEAT_ + f] : 0.f;
    kbuf[((size_t)b*KPAD_ + NONGT_ + rr)*FEAT_ + f] = (bf16)v;
  }
}

// ---------------- fused GEMM phase ----------------
// bx < 768 : Q-GEMM 128x128 tile, XCD-grouped (A-slab f32 + Wq_t L2-resident per XCD),
//            double-buffered LDS, T3 minimum 2-phase: stage(t+1) issued before MFMA(t),
//            ONE vmcnt-drain barrier per k-step.
// bx >= 768: small GEMMs, one wave per 16x16 tile (K-GEMM from roi f32 + VW-GEMM).
__global__ __launch_bounds__(256, 2) void gemm_fused_kernel(
    const float* __restrict__ roi, const bf16* __restrict__ Wq_t,
    const float* __restrict__ bq, bf16* __restrict__ qbuf,
    const bf16* __restrict__ Wk_t, const bf16* __restrict__ Vbf,
    const bf16* __restrict__ Whi, const bf16* __restrict__ Wlo,
    const float* __restrict__ bk, bf16* __restrict__ kbuf,
    bf16* __restrict__ vwT_hi, bf16* __restrict__ vwT_lo)
{
  __shared__ __align__(16) bf16 sA[2*128*32];   // 16 KB (double-buffered)
  __shared__ __align__(16) bf16 sB[2*128*32];   // 16 KB
  const int tid = threadIdx.x;
  const int w = tid >> 6, l = tid & 63;
  const int bx = blockIdx.x;
  const int fr = l & 15, fq = l >> 4, fko = fq << 3;

  if (bx < 768) {
    // ---- XCD-grouped mapping: XCD x owns mtiles {x, x+8, ...}, ctiles consecutive ----
    const int x = bx & 7, j = bx >> 3;
    const int mbase = (x + 8*(j/6)) * 128;
    const int nbase = (j % 6) * 128;
    const int wr = w >> 1, wc = w & 1;
    const int srow = tid >> 2;
    const int scol = (tid & 3) << 3;
    const float* Ag0 = roi + (size_t)(mbase + srow)*FEAT_ + scol;
    const float* Ag1 = Ag0 + (size_t)64*FEAT_;
    const bf16*  Bg0 = Wq_t + (size_t)(nbase + srow)*FEAT_ + scol;
    const bf16*  Bg1 = Bg0 + (size_t)64*FEAT_;
    f32x4 acc[4][4] = {};
    // ---- prologue: stage tile 0 into buffer 0 ----
    {
      float4 a00 = *(const float4*)Ag0, a01 = *(const float4*)(Ag0 + 4);
      float4 a10 = *(const float4*)Ag1, a11 = *(const float4*)(Ag1 + 4);
      gload16(Bg0, sB + w*512);
      gload16(Bg1, sB + 2048 + w*512);
      *(bf16x8*)(sA + srow*32 + scol) = cvt8(a00, a01);
      *(bf16x8*)(sA + (64 + srow)*32 + scol) = cvt8(a10, a11);
      __syncthreads();
    }
    for (int kt = 0; kt < 24; ++kt) {
      const int cur = (kt & 1) << 12;          // *4096 elements
      const int nxt = ((kt + 1) & 1) << 12;
      float4 p00, p01, p10, p11;
      if (kt < 23) {
        // issue next tile's loads BEFORE compute (latency hides under MFMA)
        const float* An0 = Ag0 + (kt + 1)*32;
        const float* An1 = Ag1 + (kt + 1)*32;
        p00 = *(const float4*)An0; p01 = *(const float4*)(An0 + 4);
        p10 = *(const float4*)An1; p11 = *(const float4*)(An1 + 4);
        gload16(Bg0 + (kt + 1)*32, sB + nxt + w*512);
        gload16(Bg1 + (kt + 1)*32, sB + nxt + 2048 + w*512);
      }
      bf16x8 af[4], bff[4];
      #pragma unroll
      for (int m = 0; m < 4; ++m)
        af[m] = *(const bf16x8*)(sA + cur + (wr*64 + m*16 + fr)*32 + fko);
      #pragma unroll
      for (int n = 0; n < 4; ++n)
        bff[n] = *(const bf16x8*)(sB + cur + (wc*64 + n*16 + fr)*32 + fko);
      #pragma unroll
      for (int m = 0; m < 4; ++m) {
        #pragma unroll
        for (int n = 0; n < 4; ++n)
          acc[m][n] = __builtin_amdgcn_mfma_f32_16x16x32_bf16(af[m], bff[n], acc[m][n], 0, 0, 0);
      }
      if (kt < 23) {
        *(bf16x8*)(sA + nxt + srow*32 + scol) = cvt8(p00, p01);
        *(bf16x8*)(sA + nxt + (64 + srow)*32 + scol) = cvt8(p10, p11);
      }
      __syncthreads();   // one drain per k-step (covers B gload + A ds_write)
    }
    #pragma unroll
    for (int n = 0; n < 4; ++n) {
      const int col = nbase + wc*64 + n*16 + fr;
      const float bv = bq[col];
      #pragma unroll
      for (int m = 0; m < 4; ++m) {
        const int row = mbase + wr*64 + m*16 + fq*4;
        #pragma unroll
        for (int r = 0; r < 4; ++r)
          qbuf[(size_t)(row + r)*FEAT_ + col] = (bf16)(acc[m][n][r] + bv);
      }
    }
  } else {
    // ---- small GEMMs: wave-task widx in [0, 3072) ----
    const int widx = (bx - 768)*4 + w;
    const int cbase = (widx % 48) * 16;
    const int by = widx / 48;                 // [0,64)
    f32x4 acc = {};
    if (by < 32) {
      const float* Ap = roi + ((size_t)(by >> 1)*N_ + (by & 1)*16 + fr)*FEAT_ + fko;
      const bf16* Bp = Wk_t + (size_t)(cbase + fr)*FEAT_ + fko;
      #pragma unroll
      for (int kt = 0; kt < FEAT_/32; ++kt) {
        float4 a0 = *(const float4*)(Ap + kt*32);
        float4 a1 = *(const float4*)(Ap + kt*32 + 4);
        bf16x8 b = *(const bf16x8*)(Bp + kt*32);
        acc = __builtin_amdgcn_mfma_f32_16x16x32_bf16(cvt8(a0, a1), b, acc, 0, 0, 0);
      }
      const float bv = bk[cbase + fr];
      #pragma unroll
      for (int r = 0; r < 4; ++r) {
        const int rl = (by & 1)*16 + fq*4 + r;       // local key row 0..31
        if (rl < NONGT_)
          kbuf[((size_t)(by >> 1)*KPAD_ + rl)*FEAT_ + cbase + fr] = (bf16)(acc[r] + bv);
      }
    } else {
      const int rt = by - 32;
      const bf16* Ap = Vbf + ((size_t)rt*16 + fr)*FEAT_ + fko;
      const bf16* B1 = Whi + (size_t)(cbase + fr)*FEAT_ + fko;
      const bf16* B2 = Wlo + (size_t)(cbase + fr)*FEAT_ + fko;
      f32x4 acc2 = {};
      #pragma unroll
      for (int kt = 0; kt < FEAT_/32; ++kt) {
        bf16x8 a = *(const bf16x8*)(Ap + kt*32);
        acc  = __builtin_amdgcn_mfma_f32_16x16x32_bf16(a, *(const bf16x8*)(B1 + kt*32), acc,  0, 0, 0);
        acc2 = __builtin_amdgcn_mfma_f32_16x16x32_bf16(a, *(const bf16x8*)(B2 + kt*32), acc2, 0, 0, 0);
      }
      #pragma unroll
      for (int r = 0; r < 4; ++r) {
        const int grow = rt*16 + fq*4 + r;           // 0..511
        const int b = grow >> 5, key = grow & 31;
        float vv = acc[r] + acc2[r];
        bf16 vh = (bf16)vv;
        size_t addr = ((size_t)b*FEAT_ + cbase + fr)*KPAD_ + key;
        vwT_hi[addr] = vh;
        vwT_lo[addr] = (bf16)(vv - (float)vh);
      }
    }
  }
}

// ---------------- position bias: log(max(relu(pe@Wpos+bpos),1e-6)) ----------------
__global__ __launch_bounds__(64, 4) void posbias_kernel(
    const float* __restrict__ pe, const float* __restrict__ Wpos,
    const float* __restrict__ bpos, float* __restrict__ posb)
{
  __shared__ __align__(16) float spe[NONGT_*68];
  __shared__ __align__(16) float swpT[H_*68];
  __shared__ float sbp[H_];
  const int row = blockIdx.x;
  const int l = threadIdx.x;
  const float* per = pe + (size_t)row*NONGT_*POS_;
  for (int i = l; i < NONGT_*POS_; i += 64) spe[(i >> 6)*68 + (i & 63)] = per[i];
  for (int i = l; i < POS_*H_; i += 64) swpT[(i & 7)*68 + (i >> 3)] = Wpos[i];
  if (l < H_) sbp[l] = bpos[l];
  __syncthreads();
  #pragma unroll
  for (int t = 0; t < 3; ++t) {
    int idx = t*64 + l;
    if (idx < NONGT_*H_) {
      int j = idx >> 3, h = idx & 7;
      float s = sbp[h];
      const float4* a4 = (const float4*)(spe + j*68);
      const float4* b4 = (const float4*)(swpT + h*68);
      #pragma unroll
      for (int p4 = 0; p4 < 16; ++p4) {
        float4 a = a4[p4], bv = b4[p4];
        s += a.x*bv.x + a.y*bv.y + a.z*bv.z + a.w*bv.w;
      }
      s = fmaxf(s, 0.f);
      posb[(size_t)row*160 + h*20 + j] = __logf(fmaxf(s, 1e-6f));
    }
  }
}

// ---------------- fused attention: QK^T (MFMA) + softmax + PV (MFMA) ----------------
// grid (ntile=64, b=16), 256 threads = 4 waves; wave w owns heads 2w, 2w+1.
__global__ __launch_bounds__(256, 4) void attn_kernel(
    const bf16* __restrict__ qbuf, const bf16* __restrict__ kbuf,
    const bf16* __restrict__ vwT_hi, const bf16* __restrict__ vwT_lo,
    const float* __restrict__ posb, const int* __restrict__ adj,
    const float* __restrict__ lb, const float* __restrict__ bout,
    float* __restrict__ out)
{
  __shared__ __align__(16) bf16 sph[H_*16*40];   // p hi, padded key stride 40
  __shared__ __align__(16) bf16 spl[H_*16*40];   // p lo
  const int tid = threadIdx.x;
  const int w = tid >> 6, l = tid & 63;
  const int fr = l & 15, fq = l >> 4, fko = fq << 3;
  const int row0 = blockIdx.x * 16;
  const int b = blockIdx.y;
  const size_t rabs = (size_t)b*N_ + row0 + fr;   // this lane's q-row (for q/posb/adj/lb)

  #pragma unroll
  for (int hi2 = 0; hi2 < 2; ++hi2) {
    const int h = w*2 + hi2;
    // ---- QK^T: C[key][qrow], 2 key-tiles, K=96 ----
    const bf16* kp = kbuf + (size_t)b*KPAD_*FEAT_ + h*DG_ + fko;
    const bf16* qp = qbuf + rabs*FEAT_ + h*DG_ + fko;
    f32x4 acc0 = {}, acc1 = {};
    #pragma unroll
    for (int kt = 0; kt < 3; ++kt) {
      bf16x8 qa = *(const bf16x8*)(qp + kt*32);
      bf16x8 k0 = *(const bf16x8*)(kp + (size_t)fr*FEAT_ + kt*32);
      bf16x8 k1 = *(const bf16x8*)(kp + (size_t)(16 + fr)*FEAT_ + kt*32);
      acc0 = __builtin_amdgcn_mfma_f32_16x16x32_bf16(k0, qa, acc0, 0, 0, 0);
      acc1 = __builtin_amdgcn_mfma_f32_16x16x32_bf16(k1, qa, acc1, 0, 0, 0);
    }
    // ---- bias + mask; lane holds keys {fq*4+r, 16+fq*4+r} of q-row (row0+fr) ----
    const float* pbr = posb + rabs*160 + h*20;
    const int*   adjr = adj + rabs*20;
    const float* lbr  = lb  + rabs*20;
    float lg[2][4];
    #pragma unroll
    for (int r = 0; r < 4; ++r) {
      int j0 = fq*4 + r;
      float v0 = acc0[r] * INV_SQRT_DG;
      v0 = (adjr[j0] > 0 ? v0 + pbr[j0] : NEG_) + lbr[j0];
      lg[0][r] = v0;
      int j1 = 16 + fq*4 + r;
      float v1 = acc1[r] * INV_SQRT_DG;
      if (j1 < NONGT_)      v1 = (adjr[j1] > 0 ? v1 + pbr[j1] : NEG_) + lbr[j1];
      else if (j1 >= KTOT_) v1 = -3.0e38f;
      lg[1][r] = v1;
    }
    // ---- softmax over 32 keys: 8 regs x 4 lanes (fq) ----
    float m = lg[0][0];
    #pragma unroll
    for (int jt = 0; jt < 2; ++jt)
      #pragma unroll
      for (int r = 0; r < 4; ++r) m = fmaxf(m, lg[jt][r]);
    m = fmaxf(m, __shfl_xor(m, 16));
    m = fmaxf(m, __shfl_xor(m, 32));
    float s = 0.f;
    float e[2][4];
    #pragma unroll
    for (int jt = 0; jt < 2; ++jt)
      #pragma unroll
      for (int r = 0; r < 4; ++r) { e[jt][r] = __expf(lg[jt][r] - m); s += e[jt][r]; }
    s += __shfl_xor(s, 16);
    s += __shfl_xor(s, 32);
    const float inv = 1.f / s;
    // ---- p -> hi/lo bf16 -> LDS (wave-private region, no barrier) ----
    #pragma unroll
    for (int jt = 0; jt < 2; ++jt) {
      bf16x4 ph, pl;
      #pragma unroll
      for (int r = 0; r < 4; ++r) {
        float p = e[jt][r] * inv;
        ph[r] = (bf16)p;
        pl[r] = (bf16)(p - (float)ph[r]);
      }
      const int off = (h*16 + fr)*40 + jt*16 + fq*4;
      *(bf16x4*)(sph + off) = ph;
      *(bf16x4*)(spl + off) = pl;
    }
    // ---- PV: out[16 rows x 96 cols] via 6 col-tiles, K=32 (1 k-step), 3 passes ----
    bf16x8 pa_h = *(const bf16x8*)(sph + (h*16 + fr)*40 + fko);
    bf16x8 pa_l = *(const bf16x8*)(spl + (h*16 + fr)*40 + fko);
    #pragma unroll
    for (int ct = 0; ct < 6; ++ct) {
      const int col = h*DG_ + ct*16 + fr;
      const size_t vaddr = ((size_t)b*FEAT_ + col)*KPAD_ + fko;
      bf16x8 vh = *(const bf16x8*)(vwT_hi + vaddr);
      bf16x8 vl = *(const bf16x8*)(vwT_lo + vaddr);
      f32x4 o = {};
      o = __builtin_amdgcn_mfma_f32_16x16x32_bf16(pa_h, vh, o, 0, 0, 0);
      o = __builtin_amdgcn_mfma_f32_16x16x32_bf16(pa_h, vl, o, 0, 0, 0);
      o = __builtin_amdgcn_mfma_f32_16x16x32_bf16(pa_l, vh, o, 0, 0, 0);
      const float bv = bout[col];
      #pragma unroll
      for (int r = 0; r < 4; ++r)
        out[((size_t)b*N_ + row0 + fq*4 + r)*FEAT_ + col] = o[r] + bv;
    }
  }
}

extern "C" void kernel_launch(void* const* d_in, const int* in_sizes, int n_in,
                              void* d_out, int out_size, void* d_ws, size_t ws_size,
                              hipStream_t stream) {
  const float* roi  = (const float*)d_in[0];
  const int*   adj  = (const int*)  d_in[1];
  const float* pe   = (const float*)d_in[2];
  const float* lb   = (const float*)d_in[3];
  const float* aux  = (const float*)d_in[4];
  const float* Wq   = (const float*)d_in[5];
  const float* bq   = (const float*)d_in[6];
  const float* Wk   = (const float*)d_in[7];
  const float* bk   = (const float*)d_in[8];
  const float* Wpos = (const float*)d_in[9];
  const float* bpos = (const float*)d_in[10];
  const float* m_k  = (const float*)d_in[11];
  const float* m_v  = (const float*)d_in[12];
  const float* Wout = (const float*)d_in[13];
  const float* bout = (const float*)d_in[14];
  float* out = (float*)d_out;

  char* pw = (char*)d_ws;
  auto carve = [&](size_t bytes) -> void* {
    void* r = pw; pw += (bytes + 255) & ~(size_t)255; return r;
  };
  bf16*  qbuf   = (bf16*) carve((size_t)ROWS_*FEAT_*2);
  bf16*  Wq_t   = (bf16*) carve((size_t)FEAT_*FEAT_*2);
  bf16*  Wk_t   = (bf16*) carve((size_t)FEAT_*FEAT_*2);
  bf16*  Whi    = (bf16*) carve((size_t)FEAT_*FEAT_*2);
  bf16*  Wlo    = (bf16*) carve((size_t)FEAT_*FEAT_*2);
  bf16*  Vbf    = (bf16*) carve((size_t)B_*KPAD_*FEAT_*2);
  bf16*  kbuf   = (bf16*) carve((size_t)B_*KPAD_*FEAT_*2);
  bf16*  vwT_hi = (bf16*) carve((size_t)B_*FEAT_*KPAD_*2);
  bf16*  vwT_lo = (bf16*) carve((size_t)B_*FEAT_*KPAD_*2);
  float* posb   = (float*)carve((size_t)ROWS_*160*4);

  posbias_kernel<<<dim3(16384), dim3(64), 0, stream>>>(pe, Wpos, bpos, posb);
  prep_kernel<<<dim3(1024), dim3(256), 0, stream>>>(Wq, Wk, Wout, roi, aux, m_v, m_k,
                                                    Wq_t, Wk_t, Whi, Wlo, Vbf, kbuf);
  gemm_fused_kernel<<<dim3(1536), dim3(256), 0, stream>>>(roi, Wq_t, bq, qbuf,
                                                          Wk_t, Vbf, Whi, Wlo, bk, kbuf,
                                                          vwT_hi, vwT_lo);
  attn_kernel<<<dim3(64, 16), dim3(256), 0, stream>>>(qbuf, kbuf, vwT_hi, vwT_lo,
                                                      posb, adj, lb, bout, out);
}